// Round 6
// baseline (369.817 us; speedup 1.0000x reference)
//
#include <hip/hip_runtime.h>
#include <hip/hip_fp16.h>

#define RN 4
#define XSTRIDE 132   // R + DIN

typedef float    frag_cd __attribute__((ext_vector_type(4)));
typedef _Float16 frag_h  __attribute__((ext_vector_type(8)));

// ---------------- CSR build ------------------------------------------------
__global__ void count_kernel(const int* __restrict__ ei, int E, int* __restrict__ cnt) {
    int e = blockIdx.x * 256 + threadIdx.x;
    if (e < E) atomicAdd(&cnt[ei[E + e]], 1);
}

__global__ void scanA(const int* __restrict__ cnt, int N, int* __restrict__ bsums) {
    __shared__ int s[256];
    int t = threadIdx.x, n = blockIdx.x * 256 + t;
    s[t] = (n < N) ? cnt[n] : 0;
    __syncthreads();
    for (int off = 128; off > 0; off >>= 1) {
        if (t < off) s[t] += s[t + off];
        __syncthreads();
    }
    if (t == 0) bsums[blockIdx.x] = s[0];
}

__global__ void scanB(int* __restrict__ bsums, int nb) {
    __shared__ int s[256];
    int t = threadIdx.x;
    int v = (t < nb) ? bsums[t] : 0;
    s[t] = v; __syncthreads();
    for (int off = 1; off < 256; off <<= 1) {
        int add = (t >= off) ? s[t - off] : 0;
        __syncthreads();
        s[t] += add;
        __syncthreads();
    }
    if (t < nb) bsums[t] = s[t] - v;   // exclusive
}

__global__ void scanC(const int* __restrict__ cnt, int N,
                      const int* __restrict__ bsums, int* __restrict__ offs) {
    __shared__ int s[256];
    int t = threadIdx.x, n = blockIdx.x * 256 + t;
    int v = (n < N) ? cnt[n] : 0;
    s[t] = v; __syncthreads();
    for (int off = 1; off < 256; off <<= 1) {
        int add = (t >= off) ? s[t - off] : 0;
        __syncthreads();
        s[t] += add;
        __syncthreads();
    }
    if (n < N) {
        offs[n] = bsums[blockIdx.x] + s[t] - v;
        if (n == N - 1) offs[N] = bsums[blockIdx.x] + s[t];
    }
}

__global__ void fill_kernel(const int* __restrict__ ei, int E,
                            const int* __restrict__ offs, int* __restrict__ fc,
                            int* __restrict__ csr) {
    int e = blockIdx.x * 256 + threadIdx.x;
    if (e < E) {
        int dst = ei[E + e];
        int p = offs[dst] + atomicAdd(&fc[dst], 1);
        csr[p] = ei[e];
    }
}

// ---------------- weight pre-convert: fp32 [L][4][K][128] (r<3) ------------
// -> transposed fp16 planes [l*3+r][col][K]
__global__ void conv_w(const float* __restrict__ W, _Float16* __restrict__ T,
                       int K, int total) {
    int id = blockIdx.x * 256 + threadIdx.x;
    if (id >= total) return;
    int per = K * 128;
    int lr = id / per;              // 0..5  (l*3+r)
    int l = lr / 3, r = lr - l * 3;
    int rem = id - lr * per;
    int k = rem >> 7;
    int col = rem & 127;
    float v = W[(((size_t)l * 4 + r) * K + k) * 128 + col];
    T[((size_t)lr * 128 + col) * K + k] = (_Float16)v;
}

// W1 [128][128] -> [col][k]; W2 [128][40] -> [48][128] zero-padded
__global__ void conv_w12(const float* __restrict__ W1, const float* __restrict__ W2,
                         _Float16* __restrict__ T1, _Float16* __restrict__ T2) {
    int id = blockIdx.x * 256 + threadIdx.x;
    if (id < 128 * 128) {
        int col = id >> 7, k = id & 127;
        T1[id] = (_Float16)W1[k * 128 + col];
    } else if (id < 128 * 128 + 48 * 128) {
        int j = id - 128 * 128;
        int col = j >> 7, k = j & 127;
        T2[j] = (_Float16)((col < 40) ? W2[k * 40 + col] : 0.0f);
    }
}

// x feats -> fp16 plane [N][128]
__global__ void conv_x(const float* __restrict__ x, _Float16* __restrict__ X, int total) {
    int id = blockIdx.x * 256 + threadIdx.x;
    if (id >= total) return;
    int n = id >> 7, k = id & 127;
    X[id] = (_Float16)x[(size_t)n * XSTRIDE + RN + k];
}

// ---------------- aggregate: mean over in-edges of Mb (fp16) -> fp16 -------
__global__ __launch_bounds__(256) void agg_kernel(
    const int* __restrict__ csr, const int* __restrict__ offs,
    const _Float16* __restrict__ Mb, _Float16* __restrict__ S, int N)
{
    int node = blockIdx.x * 4 + (threadIdx.x >> 6);
    int lane = threadIdx.x & 63;
    if (node >= N) return;
    int lo = offs[node], hi = offs[node + 1];
    const __half2* M2 = (const __half2*)Mb;
    float a0 = 0.0f, a1 = 0.0f;
    int e = lo;
    for (; e + 3 < hi; e += 4) {
        float2 u0 = __half22float2(M2[(size_t)csr[e]     * 64 + lane]);
        float2 u1 = __half22float2(M2[(size_t)csr[e + 1] * 64 + lane]);
        float2 u2 = __half22float2(M2[(size_t)csr[e + 2] * 64 + lane]);
        float2 u3 = __half22float2(M2[(size_t)csr[e + 3] * 64 + lane]);
        a0 += (u0.x + u1.x) + (u2.x + u3.x);
        a1 += (u0.y + u1.y) + (u2.y + u3.y);
    }
    for (; e < hi; ++e) {
        float2 u = __half22float2(M2[(size_t)csr[e] * 64 + lane]);
        a0 += u.x; a1 += u.y;
    }
    float inv = (hi > lo) ? 1.0f / (float)(hi - lo) : 0.0f;
    ((__half2*)S)[(size_t)node * 64 + lane] =
        __float22half2_rn(make_float2(a0 * inv, a1 * inv));
}

// ---------------- MFMA role-weighted GEMM, fp16, 32-row tiles --------------
// out[n][o] = relu( sum_r c_r[n] * ((v[n] @ W_r)[o] + b_r[o]) ), opt row-norm.
// Block 32 nodes x 128 cols, 4 waves; wave w covers cols [32w, 32w+32).
// 1250 blocks (~4.9/CU) + 48-VGPR accumulators -> high residency to hide
// L2 latency of direct-global frag loads (no LDS staging).
template<int KV, bool NORM>
__global__ __launch_bounds__(256) void gemm_mfma(
    const float* __restrict__ x,
    const _Float16* __restrict__ Fp,               // [N][128]
    const _Float16* __restrict__ Sp,               // KV==256 only
    const _Float16* __restrict__ W,                // [3][128][KV]
    const float* __restrict__ bias,                // [4][128]
    _Float16* __restrict__ out)                    // [N][128]
{
    __shared__ float cc[32][3];
    __shared__ float red[32][4];

    const int tid = threadIdx.x;
    const int n0 = blockIdx.x * 32;
    const int lane = tid & 63;
    const int wv = tid >> 6;
    const int q = lane >> 4;
    const int lb = lane & 15;
    const int w32 = wv * 32;

    if (tid < 32) {
        const float* xr = x + (size_t)(n0 + tid) * XSTRIDE;
        cc[tid][0] = 2.0f * xr[0];
        cc[tid][1] = xr[1];
        cc[tid][2] = xr[2];
    }
    __syncthreads();

    frag_cd acc[3][2][2];
    #pragma unroll
    for (int r = 0; r < 3; ++r)
        #pragma unroll
        for (int nt = 0; nt < 2; ++nt)
            #pragma unroll
            for (int ct = 0; ct < 2; ++ct)
                acc[r][nt][ct] = (frag_cd){0.f, 0.f, 0.f, 0.f};

    const int NCH = KV / 32;
    #pragma unroll
    for (int ch = 0; ch < NCH; ++ch) {
        const _Float16* ap; int kofs;
        if (KV == 128 || ch < 4) { ap = Fp; kofs = ch * 32; }
        else                     { ap = Sp; kofs = (ch - 4) * 32; }
        frag_h aF[2];
        #pragma unroll
        for (int nt = 0; nt < 2; ++nt)
            aF[nt] = *(const frag_h*)(ap + (size_t)(n0 + nt * 16 + lb) * 128 + kofs + q * 8);
        #pragma unroll
        for (int r = 0; r < 3; ++r) {
            #pragma unroll
            for (int ct = 0; ct < 2; ++ct) {
                frag_h bF = *(const frag_h*)(
                    W + ((size_t)(r * 128 + w32 + ct * 16 + lb)) * KV + ch * 32 + q * 8);
                #pragma unroll
                for (int nt = 0; nt < 2; ++nt)
                    acc[r][nt][ct] = __builtin_amdgcn_mfma_f32_16x16x32_f16(
                        aF[nt], bF, acc[r][nt][ct], 0, 0, 0);
            }
        }
    }

    // ---- epilogue: combine roles + bias, relu; C/D: col=lane&15, row=q*4+reg
    float vv[2][2][4];   // [nt][ct][rg]
    #pragma unroll
    for (int ct = 0; ct < 2; ++ct) {
        int col = w32 + ct * 16 + lb;
        float b0 = bias[col], b1 = bias[128 + col], b2 = bias[256 + col];
        #pragma unroll
        for (int nt = 0; nt < 2; ++nt) {
            #pragma unroll
            for (int rg = 0; rg < 4; ++rg) {
                int row = nt * 16 + q * 4 + rg;
                float v = cc[row][0] * (acc[0][nt][ct][rg] + b0)
                        + cc[row][1] * (acc[1][nt][ct][rg] + b1)
                        + cc[row][2] * (acc[2][nt][ct][rg] + b2);
                vv[nt][ct][rg] = fmaxf(v, 0.0f);
            }
        }
    }

    if (NORM) {
        #pragma unroll
        for (int nt = 0; nt < 2; ++nt) {
            #pragma unroll
            for (int rg = 0; rg < 4; ++rg) {
                float ss = vv[nt][0][rg] * vv[nt][0][rg] + vv[nt][1][rg] * vv[nt][1][rg];
                #pragma unroll
                for (int m = 1; m < 16; m <<= 1) ss += __shfl_xor(ss, m, 64);
                if (lb == 0) red[nt * 16 + q * 4 + rg][wv] = ss;
            }
        }
        __syncthreads();
        #pragma unroll
        for (int nt = 0; nt < 2; ++nt) {
            #pragma unroll
            for (int rg = 0; rg < 4; ++rg) {
                int row = nt * 16 + q * 4 + rg;
                float t = red[row][0] + red[row][1] + red[row][2] + red[row][3];
                float inv = 1.0f / fmaxf(sqrtf(t), 1e-12f);
                #pragma unroll
                for (int ct = 0; ct < 2; ++ct) {
                    int col = w32 + ct * 16 + lb;
                    out[(size_t)(n0 + row) * 128 + col] = (_Float16)(vv[nt][ct][rg] * inv);
                }
            }
        }
    } else {
        #pragma unroll
        for (int nt = 0; nt < 2; ++nt)
            #pragma unroll
            for (int ct = 0; ct < 2; ++ct)
                #pragma unroll
                for (int rg = 0; rg < 4; ++rg) {
                    int row = nt * 16 + q * 4 + rg;
                    int col = w32 + ct * 16 + lb;
                    out[(size_t)(n0 + row) * 128 + col] = (_Float16)vv[nt][ct][rg];
                }
    }
}

// ---------------- final: z=F@W1+b1; logits=z@W2+b2; log_softmax (MFMA) ------
__global__ __launch_bounds__(256) void final_mfma(
    const _Float16* __restrict__ F2,               // [N][128]
    const _Float16* __restrict__ W1T,              // [128][128] ([col][k])
    const float* __restrict__ b1,
    const _Float16* __restrict__ W2T,              // [48][128] zero-padded
    const float* __restrict__ b2,
    float* __restrict__ out)                       // N x 40
{
    __shared__ _Float16 Z[64][136];

    const int tid = threadIdx.x;
    const int n0 = blockIdx.x * 64;
    const int lane = tid & 63;
    const int wv = tid >> 6;
    const int q = lane >> 4;
    const int lb = lane & 15;
    const int w32 = wv * 32;

    // ---- z = F@W1 + b1 : block 64 rows x 128 cols, wave = 32-col slice ----
    frag_cd acc[4][2];
    #pragma unroll
    for (int nt = 0; nt < 4; ++nt)
        #pragma unroll
        for (int ct = 0; ct < 2; ++ct) acc[nt][ct] = (frag_cd){0.f, 0.f, 0.f, 0.f};

    #pragma unroll
    for (int ch = 0; ch < 4; ++ch) {
        frag_h aF[4];
        #pragma unroll
        for (int nt = 0; nt < 4; ++nt)
            aF[nt] = *(const frag_h*)(F2 + (size_t)(n0 + nt * 16 + lb) * 128 + ch * 32 + q * 8);
        #pragma unroll
        for (int ct = 0; ct < 2; ++ct) {
            frag_h bF = *(const frag_h*)(W1T + (size_t)(w32 + ct * 16 + lb) * 128 + ch * 32 + q * 8);
            #pragma unroll
            for (int nt = 0; nt < 4; ++nt)
                acc[nt][ct] = __builtin_amdgcn_mfma_f32_16x16x32_f16(aF[nt], bF, acc[nt][ct], 0, 0, 0);
        }
    }
    // z -> LDS fp16 (A-layout source for second GEMM)
    #pragma unroll
    for (int ct = 0; ct < 2; ++ct) {
        int col = w32 + ct * 16 + lb;
        float bb = b1[col];
        #pragma unroll
        for (int nt = 0; nt < 4; ++nt)
            #pragma unroll
            for (int rg = 0; rg < 4; ++rg)
                Z[nt * 16 + q * 4 + rg][col] = (_Float16)(acc[nt][ct][rg] + bb);
    }
    __syncthreads();

    // ---- logits = z@W2 + b2 : wave = 16-row tile, 48 cols (40 real) ----
    frag_cd a2[3];
    #pragma unroll
    for (int ct = 0; ct < 3; ++ct) a2[ct] = (frag_cd){0.f, 0.f, 0.f, 0.f};
    #pragma unroll
    for (int ch = 0; ch < 4; ++ch) {
        frag_h zF = *(const frag_h*)&Z[wv * 16 + lb][ch * 32 + q * 8];
        #pragma unroll
        for (int ct = 0; ct < 3; ++ct) {
            frag_h bF = *(const frag_h*)(W2T + (size_t)(ct * 16 + lb) * 128 + ch * 32 + q * 8);
            a2[ct] = __builtin_amdgcn_mfma_f32_16x16x32_f16(zF, bF, a2[ct], 0, 0, 0);
        }
    }

    // ---- log_softmax over 40 cols; lane holds cols {lb, 16+lb, 32+lb} ----
    float lg[3][4];
    #pragma unroll
    for (int ct = 0; ct < 3; ++ct) {
        int col = ct * 16 + lb;
        bool valid = col < 40;
        float bb = valid ? b2[col] : -1e30f;
        #pragma unroll
        for (int rg = 0; rg < 4; ++rg)
            lg[ct][rg] = valid ? (a2[ct][rg] + bb) : -1e30f;
    }
    #pragma unroll
    for (int rg = 0; rg < 4; ++rg) {
        float mx = fmaxf(fmaxf(lg[0][rg], lg[1][rg]), lg[2][rg]);
        #pragma unroll
        for (int m = 1; m < 16; m <<= 1) mx = fmaxf(mx, __shfl_xor(mx, m, 64));
        float sm = __expf(lg[0][rg] - mx) + __expf(lg[1][rg] - mx) + __expf(lg[2][rg] - mx);
        #pragma unroll
        for (int m = 1; m < 16; m <<= 1) sm += __shfl_xor(sm, m, 64);
        float ls = mx + __logf(sm);
        int row = n0 + wv * 16 + q * 4 + rg;
        #pragma unroll
        for (int ct = 0; ct < 3; ++ct) {
            int col = ct * 16 + lb;
            if (col < 40) out[(size_t)row * 40 + col] = lg[ct][rg] - ls;
        }
    }
}

extern "C" void kernel_launch(void* const* d_in, const int* in_sizes, int n_in,
                              void* d_out, int out_size, void* d_ws, size_t ws_size,
                              hipStream_t stream) {
    const float* x  = (const float*)d_in[0];
    const int*   ei = (const int*)d_in[1];
    const float* Wm = (const float*)d_in[2];
    const float* bm = (const float*)d_in[3];
    const float* Wa = (const float*)d_in[4];
    const float* ba = (const float*)d_in[5];
    const float* W1 = (const float*)d_in[6];
    const float* b1 = (const float*)d_in[7];
    const float* W2 = (const float*)d_in[8];
    const float* b2 = (const float*)d_in[9];
    float* out = (float*)d_out;

    const int N = in_sizes[0] / XSTRIDE;   // 40000
    const int E = in_sizes[1] / 2;         // 480000
    const int NB = (N + 255) / 256;        // 157
    const size_t P = (size_t)N * 128;      // plane elements

    // workspace carve (16B-aligned)
    _Float16* Mb  = (_Float16*)d_ws;       // msg fp16
    _Float16* X   = Mb + P;                // x feats (reused as F2 for final)
    _Float16* S   = X + P;                 // aggr
    _Float16* F1  = S + P;                 // layer-1 out
    _Float16* WmT = F1 + P;                // 6*128*128
    _Float16* WaT = WmT + 6 * 128 * 128;   // 6*128*256
    _Float16* W1T = WaT + 6 * 128 * 256;   // 128*128
    _Float16* W2T = W1T + 128 * 128;       // 48*128
    int* cnt   = (int*)(W2T + 48 * 128);
    int* offs  = cnt + N;
    int* csr   = offs + N + 1;
    int* bsums = csr + E;

    // ---- pre-convert ----
    conv_w<<<(6 * 128 * 128 + 255) / 256, 256, 0, stream>>>(Wm, WmT, 128, 6 * 128 * 128);
    conv_w<<<(6 * 128 * 256 + 255) / 256, 256, 0, stream>>>(Wa, WaT, 256, 6 * 128 * 256);
    conv_w12<<<(128 * 128 + 48 * 128 + 255) / 256, 256, 0, stream>>>(W1, W2, W1T, W2T);
    conv_x<<<(N * 128 + 255) / 256, 256, 0, stream>>>(x, X, N * 128);

    // ---- CSR build ----
    hipMemsetAsync(cnt, 0, (size_t)N * sizeof(int), stream);
    count_kernel<<<(E + 255) / 256, 256, 0, stream>>>(ei, E, cnt);
    scanA<<<NB, 256, 0, stream>>>(cnt, N, bsums);
    scanB<<<1, 256, 0, stream>>>(bsums, NB);
    scanC<<<NB, 256, 0, stream>>>(cnt, N, bsums, offs);
    hipMemsetAsync(cnt, 0, (size_t)N * sizeof(int), stream);
    fill_kernel<<<(E + 255) / 256, 256, 0, stream>>>(ei, E, offs, cnt, csr);

    const int gblk = N / 32;               // 1250
    for (int l = 0; l < 2; ++l) {
        const _Float16* fp = (l == 0) ? X : F1;
        _Float16* o = (l == 0) ? F1 : X;   // layer-2 output aliases X (becomes F2)

        gemm_mfma<128, false><<<gblk, 256, 0, stream>>>(
            x, fp, nullptr,
            WmT + (size_t)l * 3 * 128 * 128, bm + (size_t)l * 4 * 128, Mb);
        agg_kernel<<<(N + 3) / 4, 256, 0, stream>>>(csr, offs, Mb, S, N);
        gemm_mfma<256, true><<<gblk, 256, 0, stream>>>(
            x, fp, S,
            WaT + (size_t)l * 3 * 128 * 256, ba + (size_t)l * 4 * 128, o);
    }

    final_mfma<<<N / 64, 256, 0, stream>>>(X, W1T, b1, W2T, b2, out);
}

// Round 7
// 368.928 us; speedup vs baseline: 1.0024x; 1.0024x over previous
//
#include <hip/hip_runtime.h>
#include <hip/hip_fp16.h>

#define RN 4
#define XSTRIDE 132   // R + DIN

typedef float    frag_cd __attribute__((ext_vector_type(4)));
typedef _Float16 frag_h  __attribute__((ext_vector_type(8)));

// ---------------- CSR build ------------------------------------------------
__global__ void count_kernel(const int* __restrict__ ei, int E, int* __restrict__ cnt) {
    int e = blockIdx.x * 256 + threadIdx.x;
    if (e < E) atomicAdd(&cnt[ei[E + e]], 1);
}

__global__ void scanA(const int* __restrict__ cnt, int N, int* __restrict__ bsums) {
    __shared__ int s[256];
    int t = threadIdx.x, n = blockIdx.x * 256 + t;
    s[t] = (n < N) ? cnt[n] : 0;
    __syncthreads();
    for (int off = 128; off > 0; off >>= 1) {
        if (t < off) s[t] += s[t + off];
        __syncthreads();
    }
    if (t == 0) bsums[blockIdx.x] = s[0];
}

__global__ void scanB(int* __restrict__ bsums, int nb) {
    __shared__ int s[256];
    int t = threadIdx.x;
    int v = (t < nb) ? bsums[t] : 0;
    s[t] = v; __syncthreads();
    for (int off = 1; off < 256; off <<= 1) {
        int add = (t >= off) ? s[t - off] : 0;
        __syncthreads();
        s[t] += add;
        __syncthreads();
    }
    if (t < nb) bsums[t] = s[t] - v;   // exclusive
}

__global__ void scanC(const int* __restrict__ cnt, int N,
                      const int* __restrict__ bsums, int* __restrict__ offs) {
    __shared__ int s[256];
    int t = threadIdx.x, n = blockIdx.x * 256 + t;
    int v = (n < N) ? cnt[n] : 0;
    s[t] = v; __syncthreads();
    for (int off = 1; off < 256; off <<= 1) {
        int add = (t >= off) ? s[t - off] : 0;
        __syncthreads();
        s[t] += add;
        __syncthreads();
    }
    if (n < N) {
        offs[n] = bsums[blockIdx.x] + s[t] - v;
        if (n == N - 1) offs[N] = bsums[blockIdx.x] + s[t];
    }
}

__global__ void fill_kernel(const int* __restrict__ ei, int E,
                            const int* __restrict__ offs, int* __restrict__ fc,
                            int* __restrict__ csr) {
    int e = blockIdx.x * 256 + threadIdx.x;
    if (e < E) {
        int dst = ei[E + e];
        int p = offs[dst] + atomicAdd(&fc[dst], 1);
        csr[p] = ei[e];
    }
}

// ---------------- weight pre-convert: fp32 [L][4][K][128] (r<3) ------------
// -> transposed fp16 planes [l*3+r][col][K]
__global__ void conv_w(const float* __restrict__ W, _Float16* __restrict__ T,
                       int K, int total) {
    int id = blockIdx.x * 256 + threadIdx.x;
    if (id >= total) return;
    int per = K * 128;
    int lr = id / per;              // 0..5  (l*3+r)
    int l = lr / 3, r = lr - l * 3;
    int rem = id - lr * per;
    int k = rem >> 7;
    int col = rem & 127;
    float v = W[(((size_t)l * 4 + r) * K + k) * 128 + col];
    T[((size_t)lr * 128 + col) * K + k] = (_Float16)v;
}

// W1 [128][128] -> [col][k]; W2 [128][40] -> [48][128] zero-padded
__global__ void conv_w12(const float* __restrict__ W1, const float* __restrict__ W2,
                         _Float16* __restrict__ T1, _Float16* __restrict__ T2) {
    int id = blockIdx.x * 256 + threadIdx.x;
    if (id < 128 * 128) {
        int col = id >> 7, k = id & 127;
        T1[id] = (_Float16)W1[k * 128 + col];
    } else if (id < 128 * 128 + 48 * 128) {
        int j = id - 128 * 128;
        int col = j >> 7, k = j & 127;
        T2[j] = (_Float16)((col < 40) ? W2[k * 40 + col] : 0.0f);
    }
}

// x feats -> fp16 plane [N][128]
__global__ void conv_x(const float* __restrict__ x, _Float16* __restrict__ X, int total) {
    int id = blockIdx.x * 256 + threadIdx.x;
    if (id >= total) return;
    int n = id >> 7, k = id & 127;
    X[id] = (_Float16)x[(size_t)n * XSTRIDE + RN + k];
}

// ---------------- aggregate: mean over in-edges of Mb (fp16) -> fp16 -------
__global__ __launch_bounds__(256) void agg_kernel(
    const int* __restrict__ csr, const int* __restrict__ offs,
    const _Float16* __restrict__ Mb, _Float16* __restrict__ S, int N)
{
    int node = blockIdx.x * 4 + (threadIdx.x >> 6);
    int lane = threadIdx.x & 63;
    if (node >= N) return;
    int lo = offs[node], hi = offs[node + 1];
    const __half2* M2 = (const __half2*)Mb;
    float a0 = 0.0f, a1 = 0.0f;
    int e = lo;
    for (; e + 3 < hi; e += 4) {
        float2 u0 = __half22float2(M2[(size_t)csr[e]     * 64 + lane]);
        float2 u1 = __half22float2(M2[(size_t)csr[e + 1] * 64 + lane]);
        float2 u2 = __half22float2(M2[(size_t)csr[e + 2] * 64 + lane]);
        float2 u3 = __half22float2(M2[(size_t)csr[e + 3] * 64 + lane]);
        a0 += (u0.x + u1.x) + (u2.x + u3.x);
        a1 += (u0.y + u1.y) + (u2.y + u3.y);
    }
    for (; e < hi; ++e) {
        float2 u = __half22float2(M2[(size_t)csr[e] * 64 + lane]);
        a0 += u.x; a1 += u.y;
    }
    float inv = (hi > lo) ? 1.0f / (float)(hi - lo) : 0.0f;
    ((__half2*)S)[(size_t)node * 64 + lane] =
        __float22half2_rn(make_float2(a0 * inv, a1 * inv));
}

// ---------------- MFMA role-weighted GEMM, fp16, 128-row tile --------------
// out = relu( sum_r c_r (v @ W_r + b_r) ), opt row-norm.
// Key: sum_r c_r (v@W_r) == sum_r (c_r*v)@W_r, and each lane's A-frag is one
// node row -> c_r*v is one pk_mul splat per frag. Single accumulator
// acc[8][2]; per 32-k chunk: 8 A-loads + 6 B-loads feed 48 MFMAs.
// Block 128 nodes x 128 cols, 4 waves; wave w covers cols [32w, 32w+32).
template<int KV, bool NORM>
__global__ __launch_bounds__(256) void gemm_mfma(
    const float* __restrict__ x,
    const _Float16* __restrict__ Fp,               // [N][128]
    const _Float16* __restrict__ Sp,               // KV==256 only
    const _Float16* __restrict__ W,                // [3][128][KV]
    const float* __restrict__ bias,                // [4][128]
    _Float16* __restrict__ out, int N)             // [N][128]
{
    __shared__ float cc[128][3];
    __shared__ float red[128][4];

    const int tid = threadIdx.x;
    const int n0 = blockIdx.x * 128;
    const int lane = tid & 63;
    const int wv = tid >> 6;
    const int q = lane >> 4;
    const int lb = lane & 15;
    const int w32 = wv * 32;

    if (tid < 128) {
        int row = n0 + tid; if (row >= N) row = N - 1;
        const float* xr = x + (size_t)row * XSTRIDE;
        cc[tid][0] = 2.0f * xr[0];
        cc[tid][1] = xr[1];
        cc[tid][2] = xr[2];
    }
    __syncthreads();

    // per-lane row coefficients (fp32 for epilogue, fp16 for A-scaling)
    _Float16 ch16[8][3];
    #pragma unroll
    for (int nt = 0; nt < 8; ++nt)
        #pragma unroll
        for (int r = 0; r < 3; ++r)
            ch16[nt][r] = (_Float16)cc[nt * 16 + lb][r];

    frag_cd acc[8][2];
    #pragma unroll
    for (int nt = 0; nt < 8; ++nt)
        #pragma unroll
        for (int ct = 0; ct < 2; ++ct)
            acc[nt][ct] = (frag_cd){0.f, 0.f, 0.f, 0.f};

    // precompute clamped A row offsets
    size_t arow[8];
    #pragma unroll
    for (int nt = 0; nt < 8; ++nt) {
        int row = n0 + nt * 16 + lb; if (row >= N) row = N - 1;
        arow[nt] = (size_t)row * 128;
    }

    const int NCH = KV / 32;
    #pragma unroll
    for (int ch = 0; ch < NCH; ++ch) {
        const _Float16* ap; int kofs;
        if (KV == 128 || ch < 4) { ap = Fp; kofs = ch * 32; }
        else                     { ap = Sp; kofs = (ch - 4) * 32; }
        frag_h aF[8];
        #pragma unroll
        for (int nt = 0; nt < 8; ++nt)
            aF[nt] = *(const frag_h*)(ap + arow[nt] + kofs + q * 8);
        frag_h bF[3][2];
        #pragma unroll
        for (int r = 0; r < 3; ++r)
            #pragma unroll
            for (int ct = 0; ct < 2; ++ct)
                bF[r][ct] = *(const frag_h*)(
                    W + ((size_t)(r * 128 + w32 + ct * 16 + lb)) * KV + ch * 32 + q * 8);
        #pragma unroll
        for (int r = 0; r < 3; ++r) {
            #pragma unroll
            for (int nt = 0; nt < 8; ++nt) {
                frag_h sa = aF[nt] * ch16[nt][r];   // v_pk_mul_f16 splat
                #pragma unroll
                for (int ct = 0; ct < 2; ++ct)
                    acc[nt][ct] = __builtin_amdgcn_mfma_f32_16x16x32_f16(
                        sa, bF[r][ct], acc[nt][ct], 0, 0, 0);
            }
        }
    }

    // ---- epilogue: + sum_r c_r b_r, relu; C/D: col=lane&15, row=q*4+reg ----
    float vv[8][2][4];   // [nt][ct][rg]
    #pragma unroll
    for (int ct = 0; ct < 2; ++ct) {
        int col = w32 + ct * 16 + lb;
        float b0 = bias[col], b1 = bias[128 + col], b2 = bias[256 + col];
        #pragma unroll
        for (int nt = 0; nt < 8; ++nt) {
            #pragma unroll
            for (int rg = 0; rg < 4; ++rg) {
                int row = nt * 16 + q * 4 + rg;
                float v = acc[nt][ct][rg]
                        + cc[row][0] * b0 + cc[row][1] * b1 + cc[row][2] * b2;
                vv[nt][ct][rg] = fmaxf(v, 0.0f);
            }
        }
    }

    if (NORM) {
        #pragma unroll
        for (int nt = 0; nt < 8; ++nt) {
            #pragma unroll
            for (int rg = 0; rg < 4; ++rg) {
                float ss = vv[nt][0][rg] * vv[nt][0][rg] + vv[nt][1][rg] * vv[nt][1][rg];
                #pragma unroll
                for (int m = 1; m < 16; m <<= 1) ss += __shfl_xor(ss, m, 64);
                if (lb == 0) red[nt * 16 + q * 4 + rg][wv] = ss;
            }
        }
        __syncthreads();
        #pragma unroll
        for (int nt = 0; nt < 8; ++nt) {
            #pragma unroll
            for (int rg = 0; rg < 4; ++rg) {
                int row = nt * 16 + q * 4 + rg;
                float t = red[row][0] + red[row][1] + red[row][2] + red[row][3];
                float inv = 1.0f / fmaxf(sqrtf(t), 1e-12f);
                int grow = n0 + row;
                if (grow < N) {
                    #pragma unroll
                    for (int ct = 0; ct < 2; ++ct) {
                        int col = w32 + ct * 16 + lb;
                        out[(size_t)grow * 128 + col] = (_Float16)(vv[nt][ct][rg] * inv);
                    }
                }
            }
        }
    } else {
        #pragma unroll
        for (int nt = 0; nt < 8; ++nt)
            #pragma unroll
            for (int rg = 0; rg < 4; ++rg) {
                int grow = n0 + nt * 16 + q * 4 + rg;
                if (grow < N) {
                    #pragma unroll
                    for (int ct = 0; ct < 2; ++ct) {
                        int col = w32 + ct * 16 + lb;
                        out[(size_t)grow * 128 + col] = (_Float16)vv[nt][ct][rg];
                    }
                }
            }
    }
}

// ---------------- final: z=F@W1+b1; logits=z@W2+b2; log_softmax (MFMA) ------
__global__ __launch_bounds__(256) void final_mfma(
    const _Float16* __restrict__ F2,               // [N][128]
    const _Float16* __restrict__ W1T,              // [128][128] ([col][k])
    const float* __restrict__ b1,
    const _Float16* __restrict__ W2T,              // [48][128] zero-padded
    const float* __restrict__ b2,
    float* __restrict__ out)                       // N x 40
{
    __shared__ _Float16 Z[64][136];

    const int tid = threadIdx.x;
    const int n0 = blockIdx.x * 64;
    const int lane = tid & 63;
    const int wv = tid >> 6;
    const int q = lane >> 4;
    const int lb = lane & 15;
    const int w32 = wv * 32;

    // ---- z = F@W1 + b1 : block 64 rows x 128 cols, wave = 32-col slice ----
    frag_cd acc[4][2];
    #pragma unroll
    for (int nt = 0; nt < 4; ++nt)
        #pragma unroll
        for (int ct = 0; ct < 2; ++ct) acc[nt][ct] = (frag_cd){0.f, 0.f, 0.f, 0.f};

    #pragma unroll
    for (int ch = 0; ch < 4; ++ch) {
        frag_h aF[4];
        #pragma unroll
        for (int nt = 0; nt < 4; ++nt)
            aF[nt] = *(const frag_h*)(F2 + (size_t)(n0 + nt * 16 + lb) * 128 + ch * 32 + q * 8);
        #pragma unroll
        for (int ct = 0; ct < 2; ++ct) {
            frag_h bF = *(const frag_h*)(W1T + (size_t)(w32 + ct * 16 + lb) * 128 + ch * 32 + q * 8);
            #pragma unroll
            for (int nt = 0; nt < 4; ++nt)
                acc[nt][ct] = __builtin_amdgcn_mfma_f32_16x16x32_f16(aF[nt], bF, acc[nt][ct], 0, 0, 0);
        }
    }
    // z -> LDS fp16 (A-layout source for second GEMM)
    #pragma unroll
    for (int ct = 0; ct < 2; ++ct) {
        int col = w32 + ct * 16 + lb;
        float bb = b1[col];
        #pragma unroll
        for (int nt = 0; nt < 4; ++nt)
            #pragma unroll
            for (int rg = 0; rg < 4; ++rg)
                Z[nt * 16 + q * 4 + rg][col] = (_Float16)(acc[nt][ct][rg] + bb);
    }
    __syncthreads();

    // ---- logits = z@W2 + b2 : wave = 16-row tile, 48 cols (40 real) ----
    frag_cd a2[3];
    #pragma unroll
    for (int ct = 0; ct < 3; ++ct) a2[ct] = (frag_cd){0.f, 0.f, 0.f, 0.f};
    #pragma unroll
    for (int ch = 0; ch < 4; ++ch) {
        frag_h zF = *(const frag_h*)&Z[wv * 16 + lb][ch * 32 + q * 8];
        #pragma unroll
        for (int ct = 0; ct < 3; ++ct) {
            frag_h bF = *(const frag_h*)(W2T + (size_t)(ct * 16 + lb) * 128 + ch * 32 + q * 8);
            a2[ct] = __builtin_amdgcn_mfma_f32_16x16x32_f16(zF, bF, a2[ct], 0, 0, 0);
        }
    }

    // ---- log_softmax over 40 cols; lane holds cols {lb, 16+lb, 32+lb} ----
    float lg[3][4];
    #pragma unroll
    for (int ct = 0; ct < 3; ++ct) {
        int col = ct * 16 + lb;
        bool valid = col < 40;
        float bb = valid ? b2[col] : -1e30f;
        #pragma unroll
        for (int rg = 0; rg < 4; ++rg)
            lg[ct][rg] = valid ? (a2[ct][rg] + bb) : -1e30f;
    }
    #pragma unroll
    for (int rg = 0; rg < 4; ++rg) {
        float mx = fmaxf(fmaxf(lg[0][rg], lg[1][rg]), lg[2][rg]);
        #pragma unroll
        for (int m = 1; m < 16; m <<= 1) mx = fmaxf(mx, __shfl_xor(mx, m, 64));
        float sm = __expf(lg[0][rg] - mx) + __expf(lg[1][rg] - mx) + __expf(lg[2][rg] - mx);
        #pragma unroll
        for (int m = 1; m < 16; m <<= 1) sm += __shfl_xor(sm, m, 64);
        float ls = mx + __logf(sm);
        int row = n0 + wv * 16 + q * 4 + rg;
        #pragma unroll
        for (int ct = 0; ct < 3; ++ct) {
            int col = ct * 16 + lb;
            if (col < 40) out[(size_t)row * 40 + col] = lg[ct][rg] - ls;
        }
    }
}

extern "C" void kernel_launch(void* const* d_in, const int* in_sizes, int n_in,
                              void* d_out, int out_size, void* d_ws, size_t ws_size,
                              hipStream_t stream) {
    const float* x  = (const float*)d_in[0];
    const int*   ei = (const int*)d_in[1];
    const float* Wm = (const float*)d_in[2];
    const float* bm = (const float*)d_in[3];
    const float* Wa = (const float*)d_in[4];
    const float* ba = (const float*)d_in[5];
    const float* W1 = (const float*)d_in[6];
    const float* b1 = (const float*)d_in[7];
    const float* W2 = (const float*)d_in[8];
    const float* b2 = (const float*)d_in[9];
    float* out = (float*)d_out;

    const int N = in_sizes[0] / XSTRIDE;   // 40000
    const int E = in_sizes[1] / 2;         // 480000
    const int NB = (N + 255) / 256;        // 157
    const size_t P = (size_t)N * 128;      // plane elements

    // workspace carve (16B-aligned)
    _Float16* Mb  = (_Float16*)d_ws;       // msg fp16
    _Float16* X   = Mb + P;                // x feats (reused as F2 for final)
    _Float16* S   = X + P;                 // aggr
    _Float16* F1  = S + P;                 // layer-1 out
    _Float16* WmT = F1 + P;                // 6*128*128
    _Float16* WaT = WmT + 6 * 128 * 128;   // 6*128*256
    _Float16* W1T = WaT + 6 * 128 * 256;   // 128*128
    _Float16* W2T = W1T + 128 * 128;       // 48*128
    int* cnt   = (int*)(W2T + 48 * 128);
    int* offs  = cnt + N;
    int* csr   = offs + N + 1;
    int* bsums = csr + E;

    // ---- pre-convert ----
    conv_w<<<(6 * 128 * 128 + 255) / 256, 256, 0, stream>>>(Wm, WmT, 128, 6 * 128 * 128);
    conv_w<<<(6 * 128 * 256 + 255) / 256, 256, 0, stream>>>(Wa, WaT, 256, 6 * 128 * 256);
    conv_w12<<<(128 * 128 + 48 * 128 + 255) / 256, 256, 0, stream>>>(W1, W2, W1T, W2T);
    conv_x<<<(N * 128 + 255) / 256, 256, 0, stream>>>(x, X, N * 128);

    // ---- CSR build ----
    hipMemsetAsync(cnt, 0, (size_t)N * sizeof(int), stream);
    count_kernel<<<(E + 255) / 256, 256, 0, stream>>>(ei, E, cnt);
    scanA<<<NB, 256, 0, stream>>>(cnt, N, bsums);
    scanB<<<1, 256, 0, stream>>>(bsums, NB);
    scanC<<<NB, 256, 0, stream>>>(cnt, N, bsums, offs);
    hipMemsetAsync(cnt, 0, (size_t)N * sizeof(int), stream);
    fill_kernel<<<(E + 255) / 256, 256, 0, stream>>>(ei, E, offs, cnt, csr);

    const int gblk = (N + 127) / 128;      // 313
    for (int l = 0; l < 2; ++l) {
        const _Float16* fp = (l == 0) ? X : F1;
        _Float16* o = (l == 0) ? F1 : X;   // layer-2 output aliases X (becomes F2)

        gemm_mfma<128, false><<<gblk, 256, 0, stream>>>(
            x, fp, nullptr,
            WmT + (size_t)l * 3 * 128 * 128, bm + (size_t)l * 4 * 128, Mb, N);
        agg_kernel<<<(N + 3) / 4, 256, 0, stream>>>(csr, offs, Mb, S, N);
        gemm_mfma<256, true><<<gblk, 256, 0, stream>>>(
            x, fp, S,
            WaT + (size_t)l * 3 * 128 * 256, ba + (size_t)l * 4 * 128, o, N);
    }

    final_mfma<<<N / 64, 256, 0, stream>>>(X, W1T, b1, W2T, b2, out);
}

// Round 8
// 329.393 us; speedup vs baseline: 1.1227x; 1.1200x over previous
//
#include <hip/hip_runtime.h>
#include <hip/hip_fp16.h>

#define RN 4
#define XSTRIDE 132   // R + DIN

typedef float    frag_cd __attribute__((ext_vector_type(4)));
typedef _Float16 frag_h  __attribute__((ext_vector_type(8)));

// ---------------- CSR build ------------------------------------------------
__global__ void count_kernel(const int* __restrict__ ei, int E, int* __restrict__ cnt) {
    int e = blockIdx.x * 256 + threadIdx.x;
    if (e < E) atomicAdd(&cnt[ei[E + e]], 1);
}

__global__ void scanA(const int* __restrict__ cnt, int N, int* __restrict__ bsums) {
    __shared__ int s[256];
    int t = threadIdx.x, n = blockIdx.x * 256 + t;
    s[t] = (n < N) ? cnt[n] : 0;
    __syncthreads();
    for (int off = 128; off > 0; off >>= 1) {
        if (t < off) s[t] += s[t + off];
        __syncthreads();
    }
    if (t == 0) bsums[blockIdx.x] = s[0];
}

__global__ void scanB(int* __restrict__ bsums, int nb) {
    __shared__ int s[256];
    int t = threadIdx.x;
    int v = (t < nb) ? bsums[t] : 0;
    s[t] = v; __syncthreads();
    for (int off = 1; off < 256; off <<= 1) {
        int add = (t >= off) ? s[t - off] : 0;
        __syncthreads();
        s[t] += add;
        __syncthreads();
    }
    if (t < nb) bsums[t] = s[t] - v;   // exclusive
}

__global__ void scanC(const int* __restrict__ cnt, int N,
                      const int* __restrict__ bsums, int* __restrict__ offs) {
    __shared__ int s[256];
    int t = threadIdx.x, n = blockIdx.x * 256 + t;
    int v = (n < N) ? cnt[n] : 0;
    s[t] = v; __syncthreads();
    for (int off = 1; off < 256; off <<= 1) {
        int add = (t >= off) ? s[t - off] : 0;
        __syncthreads();
        s[t] += add;
        __syncthreads();
    }
    if (n < N) {
        offs[n] = bsums[blockIdx.x] + s[t] - v;
        if (n == N - 1) offs[N] = bsums[blockIdx.x] + s[t];
    }
}

__global__ void fill_kernel(const int* __restrict__ ei, int E,
                            const int* __restrict__ offs, int* __restrict__ fc,
                            int* __restrict__ csr) {
    int e = blockIdx.x * 256 + threadIdx.x;
    if (e < E) {
        int dst = ei[E + e];
        int p = offs[dst] + atomicAdd(&fc[dst], 1);
        csr[p] = ei[e];
    }
}

// ---------------- weight pre-convert: fp32 [L][4][K][128] (r<3) ------------
// -> transposed fp16 planes [l*3+r][col][K]
__global__ void conv_w(const float* __restrict__ W, _Float16* __restrict__ T,
                       int K, int total) {
    int id = blockIdx.x * 256 + threadIdx.x;
    if (id >= total) return;
    int per = K * 128;
    int lr = id / per;              // 0..5  (l*3+r)
    int l = lr / 3, r = lr - l * 3;
    int rem = id - lr * per;
    int k = rem >> 7;
    int col = rem & 127;
    float v = W[(((size_t)l * 4 + r) * K + k) * 128 + col];
    T[((size_t)lr * 128 + col) * K + k] = (_Float16)v;
}

// W1 [128][128] -> [col][k]; W2 [128][40] -> [48][128] zero-padded
__global__ void conv_w12(const float* __restrict__ W1, const float* __restrict__ W2,
                         _Float16* __restrict__ T1, _Float16* __restrict__ T2) {
    int id = blockIdx.x * 256 + threadIdx.x;
    if (id < 128 * 128) {
        int col = id >> 7, k = id & 127;
        T1[id] = (_Float16)W1[k * 128 + col];
    } else if (id < 128 * 128 + 48 * 128) {
        int j = id - 128 * 128;
        int col = j >> 7, k = j & 127;
        T2[j] = (_Float16)((col < 40) ? W2[k * 40 + col] : 0.0f);
    }
}

// x feats -> fp16 plane [N][128]
__global__ void conv_x(const float* __restrict__ x, _Float16* __restrict__ X, int total) {
    int id = blockIdx.x * 256 + threadIdx.x;
    if (id >= total) return;
    int n = id >> 7, k = id & 127;
    X[id] = (_Float16)x[(size_t)n * XSTRIDE + RN + k];
}

// ---------------- aggregate: mean over in-edges of Mb (fp16) -> fp16 -------
__global__ __launch_bounds__(256) void agg_kernel(
    const int* __restrict__ csr, const int* __restrict__ offs,
    const _Float16* __restrict__ Mb, _Float16* __restrict__ S, int N)
{
    int node = blockIdx.x * 4 + (threadIdx.x >> 6);
    int lane = threadIdx.x & 63;
    if (node >= N) return;
    int lo = offs[node], hi = offs[node + 1];
    const __half2* M2 = (const __half2*)Mb;
    float a0 = 0.0f, a1 = 0.0f;
    int e = lo;
    for (; e + 3 < hi; e += 4) {
        float2 u0 = __half22float2(M2[(size_t)csr[e]     * 64 + lane]);
        float2 u1 = __half22float2(M2[(size_t)csr[e + 1] * 64 + lane]);
        float2 u2 = __half22float2(M2[(size_t)csr[e + 2] * 64 + lane]);
        float2 u3 = __half22float2(M2[(size_t)csr[e + 3] * 64 + lane]);
        a0 += (u0.x + u1.x) + (u2.x + u3.x);
        a1 += (u0.y + u1.y) + (u2.y + u3.y);
    }
    for (; e < hi; ++e) {
        float2 u = __half22float2(M2[(size_t)csr[e] * 64 + lane]);
        a0 += u.x; a1 += u.y;
    }
    float inv = (hi > lo) ? 1.0f / (float)(hi - lo) : 0.0f;
    ((__half2*)S)[(size_t)node * 64 + lane] =
        __float22half2_rn(make_float2(a0 * inv, a1 * inv));
}

// ---------------- MFMA role-weighted GEMM, fp16, 64-row tile ---------------
// out = relu( sum_r c_r (v @ W_r + b_r) ), opt row-norm.
// sum_r c_r (v@W_r) == sum_r (c_r*v)@W_r -> single accumulator, c_r*v is one
// v_pk_mul_f16 per A-frag. 64 rows x 128 cols, 4 waves (wave = 32-col slice):
// 625 blocks (2.44/CU) for TLP. Explicit double-buffered frag prefetch: chunk
// ch+1's 10 loads issue before chunk ch's MFMAs -> waitcnt drains only the
// older buffer, next chunk stays in flight (no barrier in K-loop).
template<int KV, bool NORM>
__global__ __launch_bounds__(256) void gemm_mfma(
    const float* __restrict__ x,
    const _Float16* __restrict__ Fp,               // [N][128]
    const _Float16* __restrict__ Sp,               // KV==256 only
    const _Float16* __restrict__ W,                // [3][128][KV]
    const float* __restrict__ bias,                // [4][128]
    _Float16* __restrict__ out)                    // [N][128]
{
    __shared__ float cc[64][3];
    __shared__ float red[64][4];

    const int tid = threadIdx.x;
    const int n0 = blockIdx.x * 64;
    const int lane = tid & 63;
    const int wv = tid >> 6;
    const int q = lane >> 4;
    const int lb = lane & 15;
    const int w32 = wv * 32;

    if (tid < 64) {
        const float* xr = x + (size_t)(n0 + tid) * XSTRIDE;
        cc[tid][0] = 2.0f * xr[0];
        cc[tid][1] = xr[1];
        cc[tid][2] = xr[2];
    }
    __syncthreads();

    // per-lane row coefficients (fp16 for A-scaling)
    _Float16 ch16[4][3];
    #pragma unroll
    for (int nt = 0; nt < 4; ++nt)
        #pragma unroll
        for (int r = 0; r < 3; ++r)
            ch16[nt][r] = (_Float16)cc[nt * 16 + lb][r];

    frag_cd acc[4][2];
    #pragma unroll
    for (int nt = 0; nt < 4; ++nt)
        #pragma unroll
        for (int ct = 0; ct < 2; ++ct)
            acc[nt][ct] = (frag_cd){0.f, 0.f, 0.f, 0.f};

    // B row base offsets (per-lane constant)
    size_t wrow[3][2];
    #pragma unroll
    for (int r = 0; r < 3; ++r)
        #pragma unroll
        for (int ct = 0; ct < 2; ++ct)
            wrow[r][ct] = ((size_t)(r * 128 + w32 + ct * 16 + lb)) * KV;

    const int NCH = KV / 32;
    frag_h aF[2][4], bF[2][6];

    // prologue: load chunk 0 into buffer 0
    {
        const int kofs = 0;
        #pragma unroll
        for (int nt = 0; nt < 4; ++nt)
            aF[0][nt] = *(const frag_h*)(Fp + (size_t)(n0 + nt * 16 + lb) * 128 + kofs + q * 8);
        #pragma unroll
        for (int r = 0; r < 3; ++r)
            #pragma unroll
            for (int ct = 0; ct < 2; ++ct)
                bF[0][r * 2 + ct] = *(const frag_h*)(W + wrow[r][ct] + q * 8);
    }

    #pragma unroll
    for (int ch = 0; ch < NCH; ++ch) {
        const int cur = ch & 1, nxt = cur ^ 1;
        if (ch + 1 < NCH) {   // prefetch next chunk
            const int c1 = ch + 1;
            const _Float16* ap; int kofs;
            if (KV == 128 || c1 < 4) { ap = Fp; kofs = c1 * 32; }
            else                     { ap = Sp; kofs = (c1 - 4) * 32; }
            #pragma unroll
            for (int nt = 0; nt < 4; ++nt)
                aF[nxt][nt] = *(const frag_h*)(ap + (size_t)(n0 + nt * 16 + lb) * 128 + kofs + q * 8);
            #pragma unroll
            for (int r = 0; r < 3; ++r)
                #pragma unroll
                for (int ct = 0; ct < 2; ++ct)
                    bF[nxt][r * 2 + ct] = *(const frag_h*)(W + wrow[r][ct] + c1 * 32 + q * 8);
        }
        #pragma unroll
        for (int r = 0; r < 3; ++r) {
            #pragma unroll
            for (int nt = 0; nt < 4; ++nt) {
                frag_h sa = aF[cur][nt] * ch16[nt][r];   // v_pk_mul_f16 splat
                #pragma unroll
                for (int ct = 0; ct < 2; ++ct)
                    acc[nt][ct] = __builtin_amdgcn_mfma_f32_16x16x32_f16(
                        sa, bF[cur][r * 2 + ct], acc[nt][ct], 0, 0, 0);
            }
        }
    }

    // ---- epilogue: + sum_r c_r b_r, relu; C/D: col=lane&15, row=q*4+reg ----
    float vv[4][2][4];   // [nt][ct][rg]
    #pragma unroll
    for (int ct = 0; ct < 2; ++ct) {
        int col = w32 + ct * 16 + lb;
        float b0 = bias[col], b1 = bias[128 + col], b2 = bias[256 + col];
        #pragma unroll
        for (int nt = 0; nt < 4; ++nt) {
            #pragma unroll
            for (int rg = 0; rg < 4; ++rg) {
                int row = nt * 16 + q * 4 + rg;
                float v = acc[nt][ct][rg]
                        + cc[row][0] * b0 + cc[row][1] * b1 + cc[row][2] * b2;
                vv[nt][ct][rg] = fmaxf(v, 0.0f);
            }
        }
    }

    if (NORM) {
        #pragma unroll
        for (int nt = 0; nt < 4; ++nt) {
            #pragma unroll
            for (int rg = 0; rg < 4; ++rg) {
                float ss = vv[nt][0][rg] * vv[nt][0][rg] + vv[nt][1][rg] * vv[nt][1][rg];
                #pragma unroll
                for (int m = 1; m < 16; m <<= 1) ss += __shfl_xor(ss, m, 64);
                if (lb == 0) red[nt * 16 + q * 4 + rg][wv] = ss;
            }
        }
        __syncthreads();
        #pragma unroll
        for (int nt = 0; nt < 4; ++nt) {
            #pragma unroll
            for (int rg = 0; rg < 4; ++rg) {
                int row = nt * 16 + q * 4 + rg;
                float t = red[row][0] + red[row][1] + red[row][2] + red[row][3];
                float inv = 1.0f / fmaxf(sqrtf(t), 1e-12f);
                #pragma unroll
                for (int ct = 0; ct < 2; ++ct) {
                    int col = w32 + ct * 16 + lb;
                    out[(size_t)(n0 + row) * 128 + col] = (_Float16)(vv[nt][ct][rg] * inv);
                }
            }
        }
    } else {
        #pragma unroll
        for (int nt = 0; nt < 4; ++nt)
            #pragma unroll
            for (int ct = 0; ct < 2; ++ct)
                #pragma unroll
                for (int rg = 0; rg < 4; ++rg) {
                    int row = nt * 16 + q * 4 + rg;
                    int col = w32 + ct * 16 + lb;
                    out[(size_t)(n0 + row) * 128 + col] = (_Float16)vv[nt][ct][rg];
                }
    }
}

// ---------------- final: z=F@W1+b1; logits=z@W2+b2; log_softmax (MFMA) ------
__global__ __launch_bounds__(256) void final_mfma(
    const _Float16* __restrict__ F2,               // [N][128]
    const _Float16* __restrict__ W1T,              // [128][128] ([col][k])
    const float* __restrict__ b1,
    const _Float16* __restrict__ W2T,              // [48][128] zero-padded
    const float* __restrict__ b2,
    float* __restrict__ out)                       // N x 40
{
    __shared__ _Float16 Z[64][136];

    const int tid = threadIdx.x;
    const int n0 = blockIdx.x * 64;
    const int lane = tid & 63;
    const int wv = tid >> 6;
    const int q = lane >> 4;
    const int lb = lane & 15;
    const int w32 = wv * 32;

    // ---- z = F@W1 + b1 : block 64 rows x 128 cols, wave = 32-col slice ----
    frag_cd acc[4][2];
    #pragma unroll
    for (int nt = 0; nt < 4; ++nt)
        #pragma unroll
        for (int ct = 0; ct < 2; ++ct) acc[nt][ct] = (frag_cd){0.f, 0.f, 0.f, 0.f};

    #pragma unroll
    for (int ch = 0; ch < 4; ++ch) {
        frag_h aF[4];
        #pragma unroll
        for (int nt = 0; nt < 4; ++nt)
            aF[nt] = *(const frag_h*)(F2 + (size_t)(n0 + nt * 16 + lb) * 128 + ch * 32 + q * 8);
        #pragma unroll
        for (int ct = 0; ct < 2; ++ct) {
            frag_h bF = *(const frag_h*)(W1T + (size_t)(w32 + ct * 16 + lb) * 128 + ch * 32 + q * 8);
            #pragma unroll
            for (int nt = 0; nt < 4; ++nt)
                acc[nt][ct] = __builtin_amdgcn_mfma_f32_16x16x32_f16(aF[nt], bF, acc[nt][ct], 0, 0, 0);
        }
    }
    // z -> LDS fp16 (A-layout source for second GEMM)
    #pragma unroll
    for (int ct = 0; ct < 2; ++ct) {
        int col = w32 + ct * 16 + lb;
        float bb = b1[col];
        #pragma unroll
        for (int nt = 0; nt < 4; ++nt)
            #pragma unroll
            for (int rg = 0; rg < 4; ++rg)
                Z[nt * 16 + q * 4 + rg][col] = (_Float16)(acc[nt][ct][rg] + bb);
    }
    __syncthreads();

    // ---- logits = z@W2 + b2 : wave = 16-row tile, 48 cols (40 real) ----
    frag_cd a2[3];
    #pragma unroll
    for (int ct = 0; ct < 3; ++ct) a2[ct] = (frag_cd){0.f, 0.f, 0.f, 0.f};
    #pragma unroll
    for (int ch = 0; ch < 4; ++ch) {
        frag_h zF = *(const frag_h*)&Z[wv * 16 + lb][ch * 32 + q * 8];
        #pragma unroll
        for (int ct = 0; ct < 3; ++ct) {
            frag_h bF = *(const frag_h*)(W2T + (size_t)(ct * 16 + lb) * 128 + ch * 32 + q * 8);
            a2[ct] = __builtin_amdgcn_mfma_f32_16x16x32_f16(zF, bF, a2[ct], 0, 0, 0);
        }
    }

    // ---- log_softmax over 40 cols; lane holds cols {lb, 16+lb, 32+lb} ----
    float lg[3][4];
    #pragma unroll
    for (int ct = 0; ct < 3; ++ct) {
        int col = ct * 16 + lb;
        bool valid = col < 40;
        float bb = valid ? b2[col] : -1e30f;
        #pragma unroll
        for (int rg = 0; rg < 4; ++rg)
            lg[ct][rg] = valid ? (a2[ct][rg] + bb) : -1e30f;
    }
    #pragma unroll
    for (int rg = 0; rg < 4; ++rg) {
        float mx = fmaxf(fmaxf(lg[0][rg], lg[1][rg]), lg[2][rg]);
        #pragma unroll
        for (int m = 1; m < 16; m <<= 1) mx = fmaxf(mx, __shfl_xor(mx, m, 64));
        float sm = __expf(lg[0][rg] - mx) + __expf(lg[1][rg] - mx) + __expf(lg[2][rg] - mx);
        #pragma unroll
        for (int m = 1; m < 16; m <<= 1) sm += __shfl_xor(sm, m, 64);
        float ls = mx + __logf(sm);
        int row = n0 + wv * 16 + q * 4 + rg;
        #pragma unroll
        for (int ct = 0; ct < 3; ++ct) {
            int col = ct * 16 + lb;
            if (col < 40) out[(size_t)row * 40 + col] = lg[ct][rg] - ls;
        }
    }
}

extern "C" void kernel_launch(void* const* d_in, const int* in_sizes, int n_in,
                              void* d_out, int out_size, void* d_ws, size_t ws_size,
                              hipStream_t stream) {
    const float* x  = (const float*)d_in[0];
    const int*   ei = (const int*)d_in[1];
    const float* Wm = (const float*)d_in[2];
    const float* bm = (const float*)d_in[3];
    const float* Wa = (const float*)d_in[4];
    const float* ba = (const float*)d_in[5];
    const float* W1 = (const float*)d_in[6];
    const float* b1 = (const float*)d_in[7];
    const float* W2 = (const float*)d_in[8];
    const float* b2 = (const float*)d_in[9];
    float* out = (float*)d_out;

    const int N = in_sizes[0] / XSTRIDE;   // 40000
    const int E = in_sizes[1] / 2;         // 480000
    const int NB = (N + 255) / 256;        // 157
    const size_t P = (size_t)N * 128;      // plane elements

    // workspace carve (16B-aligned)
    _Float16* Mb  = (_Float16*)d_ws;       // msg fp16
    _Float16* X   = Mb + P;                // x feats (reused as F2 for final)
    _Float16* S   = X + P;                 // aggr
    _Float16* F1  = S + P;                 // layer-1 out
    _Float16* WmT = F1 + P;                // 6*128*128
    _Float16* WaT = WmT + 6 * 128 * 128;   // 6*128*256
    _Float16* W1T = WaT + 6 * 128 * 256;   // 128*128
    _Float16* W2T = W1T + 128 * 128;       // 48*128
    int* cnt   = (int*)(W2T + 48 * 128);
    int* offs  = cnt + N;
    int* csr   = offs + N + 1;
    int* bsums = csr + E;

    // ---- pre-convert ----
    conv_w<<<(6 * 128 * 128 + 255) / 256, 256, 0, stream>>>(Wm, WmT, 128, 6 * 128 * 128);
    conv_w<<<(6 * 128 * 256 + 255) / 256, 256, 0, stream>>>(Wa, WaT, 256, 6 * 128 * 256);
    conv_w12<<<(128 * 128 + 48 * 128 + 255) / 256, 256, 0, stream>>>(W1, W2, W1T, W2T);
    conv_x<<<(N * 128 + 255) / 256, 256, 0, stream>>>(x, X, N * 128);

    // ---- CSR build ----
    hipMemsetAsync(cnt, 0, (size_t)N * sizeof(int), stream);
    count_kernel<<<(E + 255) / 256, 256, 0, stream>>>(ei, E, cnt);
    scanA<<<NB, 256, 0, stream>>>(cnt, N, bsums);
    scanB<<<1, 256, 0, stream>>>(bsums, NB);
    scanC<<<NB, 256, 0, stream>>>(cnt, N, bsums, offs);
    hipMemsetAsync(cnt, 0, (size_t)N * sizeof(int), stream);
    fill_kernel<<<(E + 255) / 256, 256, 0, stream>>>(ei, E, offs, cnt, csr);

    const int gblk = N / 64;               // 625
    for (int l = 0; l < 2; ++l) {
        const _Float16* fp = (l == 0) ? X : F1;
        _Float16* o = (l == 0) ? F1 : X;   // layer-2 output aliases X (becomes F2)

        gemm_mfma<128, false><<<gblk, 256, 0, stream>>>(
            x, fp, nullptr,
            WmT + (size_t)l * 3 * 128 * 128, bm + (size_t)l * 4 * 128, Mb);
        agg_kernel<<<(N + 3) / 4, 256, 0, stream>>>(csr, offs, Mb, S, N);
        gemm_mfma<256, true><<<gblk, 256, 0, stream>>>(
            x, fp, S,
            WaT + (size_t)l * 3 * 128 * 256, ba + (size_t)l * 4 * 128, o);
    }

    final_mfma<<<N / 64, 256, 0, stream>>>(X, W1T, b1, W2T, b2, out);
}

// Round 9
// 307.500 us; speedup vs baseline: 1.2027x; 1.0712x over previous
//
#include <hip/hip_runtime.h>
#include <hip/hip_fp16.h>

#define RN 4
#define XSTRIDE 132   // R + DIN

typedef float    frag_cd __attribute__((ext_vector_type(4)));
typedef _Float16 frag_h  __attribute__((ext_vector_type(8)));

// ---------------- CSR build ------------------------------------------------
__global__ void count_kernel(const int* __restrict__ ei, int E, int* __restrict__ cnt) {
    int e = blockIdx.x * 256 + threadIdx.x;
    if (e < E) atomicAdd(&cnt[ei[E + e]], 1);
}

__global__ void scanA(const int* __restrict__ cnt, int N, int* __restrict__ bsums) {
    __shared__ int s[256];
    int t = threadIdx.x, n = blockIdx.x * 256 + t;
    s[t] = (n < N) ? cnt[n] : 0;
    __syncthreads();
    for (int off = 128; off > 0; off >>= 1) {
        if (t < off) s[t] += s[t + off];
        __syncthreads();
    }
    if (t == 0) bsums[blockIdx.x] = s[0];
}

__global__ void scanB(int* __restrict__ bsums, int nb) {
    __shared__ int s[256];
    int t = threadIdx.x;
    int v = (t < nb) ? bsums[t] : 0;
    s[t] = v; __syncthreads();
    for (int off = 1; off < 256; off <<= 1) {
        int add = (t >= off) ? s[t - off] : 0;
        __syncthreads();
        s[t] += add;
        __syncthreads();
    }
    if (t < nb) bsums[t] = s[t] - v;   // exclusive
}

__global__ void scanC(const int* __restrict__ cnt, int N,
                      const int* __restrict__ bsums, int* __restrict__ offs) {
    __shared__ int s[256];
    int t = threadIdx.x, n = blockIdx.x * 256 + t;
    int v = (n < N) ? cnt[n] : 0;
    s[t] = v; __syncthreads();
    for (int off = 1; off < 256; off <<= 1) {
        int add = (t >= off) ? s[t - off] : 0;
        __syncthreads();
        s[t] += add;
        __syncthreads();
    }
    if (n < N) {
        offs[n] = bsums[blockIdx.x] + s[t] - v;
        if (n == N - 1) offs[N] = bsums[blockIdx.x] + s[t];
    }
}

__global__ void fill_kernel(const int* __restrict__ ei, int E,
                            const int* __restrict__ offs, int* __restrict__ fc,
                            int* __restrict__ csr) {
    int e = blockIdx.x * 256 + threadIdx.x;
    if (e < E) {
        int dst = ei[E + e];
        int p = offs[dst] + atomicAdd(&fc[dst], 1);
        csr[p] = ei[e];
    }
}

// ---------------- merged weight pre-convert --------------------------------
// Wm [2][4][128][128] (r<3) -> WmT [6][128][128] ([col][k])
// Wa [2][4][256][128] (r<3) -> WaT [6][128][256]
// W1 [128][128] -> W1T [128][128] ([col][k]); W2 [128][40] -> W2T [48][128] pad
#define CW_M  (6 * 128 * 128)
#define CW_A  (6 * 128 * 256)
#define CW_1  (128 * 128)
#define CW_2  (48 * 128)
__global__ void conv_all(const float* __restrict__ Wm, const float* __restrict__ Wa,
                         const float* __restrict__ W1, const float* __restrict__ W2,
                         _Float16* __restrict__ WmT, _Float16* __restrict__ WaT,
                         _Float16* __restrict__ W1T, _Float16* __restrict__ W2T) {
    int id = blockIdx.x * 256 + threadIdx.x;
    if (id < CW_M) {
        const int K = 128;
        int per = K * 128;
        int lr = id / per;  int l = lr / 3, r = lr - l * 3;
        int rem = id - lr * per;
        int k = rem >> 7, col = rem & 127;
        WmT[((size_t)lr * 128 + col) * K + k] =
            (_Float16)Wm[(((size_t)l * 4 + r) * K + k) * 128 + col];
    } else if (id < CW_M + CW_A) {
        int j = id - CW_M;
        const int K = 256;
        int per = K * 128;
        int lr = j / per;  int l = lr / 3, r = lr - l * 3;
        int rem = j - lr * per;
        int k = rem >> 7, col = rem & 127;
        WaT[((size_t)lr * 128 + col) * K + k] =
            (_Float16)Wa[(((size_t)l * 4 + r) * K + k) * 128 + col];
    } else if (id < CW_M + CW_A + CW_1) {
        int j = id - CW_M - CW_A;
        int col = j >> 7, k = j & 127;
        W1T[j] = (_Float16)W1[k * 128 + col];
    } else if (id < CW_M + CW_A + CW_1 + CW_2) {
        int j = id - CW_M - CW_A - CW_1;
        int col = j >> 7, k = j & 127;
        W2T[j] = (_Float16)((col < 40) ? W2[k * 40 + col] : 0.0f);
    }
}

// x feats -> fp16 plane [N][128]
__global__ void conv_x(const float* __restrict__ x, _Float16* __restrict__ X, int total) {
    int id = blockIdx.x * 256 + threadIdx.x;
    if (id >= total) return;
    int n = id >> 7, k = id & 127;
    X[id] = (_Float16)x[(size_t)n * XSTRIDE + RN + k];
}

// ---------------- aggregate: mean over in-edges of Mb (fp16) ---------------
// 2 nodes per wave (half-wave = 32 lanes x 8 B covers one 256-B row);
// 4-edge unroll keeps 4 independent loads in flight per lane.
__global__ __launch_bounds__(256) void agg_kernel(
    const int* __restrict__ csr, const int* __restrict__ offs,
    const _Float16* __restrict__ Mb, _Float16* __restrict__ S, int N)
{
    int node = blockIdx.x * 8 + (threadIdx.x >> 5);
    int lane = threadIdx.x & 31;
    if (node >= N) return;
    int lo = offs[node], hi = offs[node + 1];
    const uint2* M2 = (const uint2*)Mb;     // row = 32 x uint2
    float a0 = 0.f, a1 = 0.f, a2 = 0.f, a3 = 0.f;
    int e = lo;
    for (; e + 3 < hi; e += 4) {
        #pragma unroll
        for (int j = 0; j < 4; ++j) {
            uint2 u = M2[(size_t)csr[e + j] * 32 + lane];
            float2 f0 = __half22float2(*(const __half2*)&u.x);
            float2 f1 = __half22float2(*(const __half2*)&u.y);
            a0 += f0.x; a1 += f0.y; a2 += f1.x; a3 += f1.y;
        }
    }
    for (; e < hi; ++e) {
        uint2 u = M2[(size_t)csr[e] * 32 + lane];
        float2 f0 = __half22float2(*(const __half2*)&u.x);
        float2 f1 = __half22float2(*(const __half2*)&u.y);
        a0 += f0.x; a1 += f0.y; a2 += f1.x; a3 += f1.y;
    }
    float inv = (hi > lo) ? 1.0f / (float)(hi - lo) : 0.0f;
    __half2 h0 = __float22half2_rn(make_float2(a0 * inv, a1 * inv));
    __half2 h1 = __float22half2_rn(make_float2(a2 * inv, a3 * inv));
    uint2 st; st.x = *(const uint*)&h0; st.y = *(const uint*)&h1;
    ((uint2*)S)[(size_t)node * 32 + lane] = st;
}

// ---------------- MFMA role-weighted GEMM, fp16, 64-row tile ---------------
// out = relu( sum_r c_r (v @ W_r + b_r) ), opt row-norm.
// sum_r c_r (v@W_r) == sum_r (c_r*v)@W_r -> single accumulator; c_r*v is one
// v_pk_mul_f16 splat per A-frag. Block 64 rows x 128 cols, 4 waves
// (wave = 32-col slice), 625 blocks. TRIPLE-buffered frag prefetch: chunks
// ch+1 and ch+2 stay in flight during chunk ch's MFMA phase (~440 cyc of
// compute in flight vs ~400-500 cyc L2/L3 latency). No barrier in K-loop.
template<int KV, bool NORM>
__global__ __launch_bounds__(256) void gemm_mfma(
    const float* __restrict__ x,
    const _Float16* __restrict__ Fp,               // [N][128]
    const _Float16* __restrict__ Sp,               // KV==256 only
    const _Float16* __restrict__ W,                // [3][128][KV]
    const float* __restrict__ bias,                // [4][128]
    _Float16* __restrict__ out)                    // [N][128]
{
    __shared__ float cc[64][3];
    __shared__ float red[64][4];

    const int tid = threadIdx.x;
    const int n0 = blockIdx.x * 64;
    const int lane = tid & 63;
    const int wv = tid >> 6;
    const int q = lane >> 4;
    const int lb = lane & 15;
    const int w32 = wv * 32;

    if (tid < 64) {
        const float* xr = x + (size_t)(n0 + tid) * XSTRIDE;
        cc[tid][0] = 2.0f * xr[0];
        cc[tid][1] = xr[1];
        cc[tid][2] = xr[2];
    }
    __syncthreads();

    _Float16 ch16[4][3];
    #pragma unroll
    for (int nt = 0; nt < 4; ++nt)
        #pragma unroll
        for (int r = 0; r < 3; ++r)
            ch16[nt][r] = (_Float16)cc[nt * 16 + lb][r];

    frag_cd acc[4][2];
    #pragma unroll
    for (int nt = 0; nt < 4; ++nt)
        #pragma unroll
        for (int ct = 0; ct < 2; ++ct)
            acc[nt][ct] = (frag_cd){0.f, 0.f, 0.f, 0.f};

    size_t wrow[3][2];
    #pragma unroll
    for (int r = 0; r < 3; ++r)
        #pragma unroll
        for (int ct = 0; ct < 2; ++ct)
            wrow[r][ct] = ((size_t)(r * 128 + w32 + ct * 16 + lb)) * KV + q * 8;

    size_t arow[4];
    #pragma unroll
    for (int nt = 0; nt < 4; ++nt)
        arow[nt] = (size_t)(n0 + nt * 16 + lb) * 128 + q * 8;

    const int NCH = KV / 32;
    frag_h aF[3][4], bF[3][6];

    auto loadChunk = [&](int c, int buf) {
        const _Float16* ap; int kofs;
        if (KV == 128 || c < 4) { ap = Fp; kofs = c * 32; }
        else                    { ap = Sp; kofs = (c - 4) * 32; }
        #pragma unroll
        for (int nt = 0; nt < 4; ++nt)
            aF[buf][nt] = *(const frag_h*)(ap + arow[nt] + kofs);
        #pragma unroll
        for (int r = 0; r < 3; ++r)
            #pragma unroll
            for (int ct = 0; ct < 2; ++ct)
                bF[buf][r * 2 + ct] = *(const frag_h*)(W + wrow[r][ct] + c * 32);
    };

    loadChunk(0, 0);
    loadChunk(1, 1);

    #pragma unroll
    for (int ch = 0; ch < NCH; ++ch) {
        if (ch + 2 < NCH) loadChunk(ch + 2, (ch + 2) % 3);
        const int cur = ch % 3;
        #pragma unroll
        for (int r = 0; r < 3; ++r) {
            #pragma unroll
            for (int nt = 0; nt < 4; ++nt) {
                frag_h sa = aF[cur][nt] * ch16[nt][r];   // v_pk_mul_f16 splat
                #pragma unroll
                for (int ct = 0; ct < 2; ++ct)
                    acc[nt][ct] = __builtin_amdgcn_mfma_f32_16x16x32_f16(
                        sa, bF[cur][r * 2 + ct], acc[nt][ct], 0, 0, 0);
            }
        }
    }

    // ---- epilogue: + sum_r c_r b_r, relu; C/D: col=lane&15, row=q*4+reg ----
    float vv[4][2][4];   // [nt][ct][rg]
    #pragma unroll
    for (int ct = 0; ct < 2; ++ct) {
        int col = w32 + ct * 16 + lb;
        float b0 = bias[col], b1 = bias[128 + col], b2 = bias[256 + col];
        #pragma unroll
        for (int nt = 0; nt < 4; ++nt) {
            #pragma unroll
            for (int rg = 0; rg < 4; ++rg) {
                int row = nt * 16 + q * 4 + rg;
                float v = acc[nt][ct][rg]
                        + cc[row][0] * b0 + cc[row][1] * b1 + cc[row][2] * b2;
                vv[nt][ct][rg] = fmaxf(v, 0.0f);
            }
        }
    }

    if (NORM) {
        #pragma unroll
        for (int nt = 0; nt < 4; ++nt) {
            #pragma unroll
            for (int rg = 0; rg < 4; ++rg) {
                float ss = vv[nt][0][rg] * vv[nt][0][rg] + vv[nt][1][rg] * vv[nt][1][rg];
                #pragma unroll
                for (int m = 1; m < 16; m <<= 1) ss += __shfl_xor(ss, m, 64);
                if (lb == 0) red[nt * 16 + q * 4 + rg][wv] = ss;
            }
        }
        __syncthreads();
        #pragma unroll
        for (int nt = 0; nt < 4; ++nt) {
            #pragma unroll
            for (int rg = 0; rg < 4; ++rg) {
                int row = nt * 16 + q * 4 + rg;
                float t = red[row][0] + red[row][1] + red[row][2] + red[row][3];
                float inv = 1.0f / fmaxf(sqrtf(t), 1e-12f);
                #pragma unroll
                for (int ct = 0; ct < 2; ++ct) {
                    int col = w32 + ct * 16 + lb;
                    out[(size_t)(n0 + row) * 128 + col] = (_Float16)(vv[nt][ct][rg] * inv);
                }
            }
        }
    } else {
        #pragma unroll
        for (int nt = 0; nt < 4; ++nt)
            #pragma unroll
            for (int ct = 0; ct < 2; ++ct)
                #pragma unroll
                for (int rg = 0; rg < 4; ++rg) {
                    int row = nt * 16 + q * 4 + rg;
                    int col = w32 + ct * 16 + lb;
                    out[(size_t)(n0 + row) * 128 + col] = (_Float16)vv[nt][ct][rg];
                }
    }
}

// ---------------- final: z=F@W1+b1; logits=z@W2+b2; log_softmax (MFMA) ------
__global__ __launch_bounds__(256) void final_mfma(
    const _Float16* __restrict__ F2,               // [N][128]
    const _Float16* __restrict__ W1T,              // [128][128] ([col][k])
    const float* __restrict__ b1,
    const _Float16* __restrict__ W2T,              // [48][128] zero-padded
    const float* __restrict__ b2,
    float* __restrict__ out)                       // N x 40
{
    __shared__ _Float16 Z[64][136];

    const int tid = threadIdx.x;
    const int n0 = blockIdx.x * 64;
    const int lane = tid & 63;
    const int wv = tid >> 6;
    const int q = lane >> 4;
    const int lb = lane & 15;
    const int w32 = wv * 32;

    // ---- z = F@W1 + b1 : block 64 rows x 128 cols, wave = 32-col slice ----
    frag_cd acc[4][2];
    #pragma unroll
    for (int nt = 0; nt < 4; ++nt)
        #pragma unroll
        for (int ct = 0; ct < 2; ++ct) acc[nt][ct] = (frag_cd){0.f, 0.f, 0.f, 0.f};

    #pragma unroll
    for (int ch = 0; ch < 4; ++ch) {
        frag_h aF[4];
        #pragma unroll
        for (int nt = 0; nt < 4; ++nt)
            aF[nt] = *(const frag_h*)(F2 + (size_t)(n0 + nt * 16 + lb) * 128 + ch * 32 + q * 8);
        #pragma unroll
        for (int ct = 0; ct < 2; ++ct) {
            frag_h bF = *(const frag_h*)(W1T + (size_t)(w32 + ct * 16 + lb) * 128 + ch * 32 + q * 8);
            #pragma unroll
            for (int nt = 0; nt < 4; ++nt)
                acc[nt][ct] = __builtin_amdgcn_mfma_f32_16x16x32_f16(aF[nt], bF, acc[nt][ct], 0, 0, 0);
        }
    }
    // z -> LDS fp16 (A-layout source for second GEMM)
    #pragma unroll
    for (int ct = 0; ct < 2; ++ct) {
        int col = w32 + ct * 16 + lb;
        float bb = b1[col];
        #pragma unroll
        for (int nt = 0; nt < 4; ++nt)
            #pragma unroll
            for (int rg = 0; rg < 4; ++rg)
                Z[nt * 16 + q * 4 + rg][col] = (_Float16)(acc[nt][ct][rg] + bb);
    }
    __syncthreads();

    // ---- logits = z@W2 + b2 : wave = 16-row tile, 48 cols (40 real) ----
    frag_cd a2[3];
    #pragma unroll
    for (int ct = 0; ct < 3; ++ct) a2[ct] = (frag_cd){0.f, 0.f, 0.f, 0.f};
    #pragma unroll
    for (int ch = 0; ch < 4; ++ch) {
        frag_h zF = *(const frag_h*)&Z[wv * 16 + lb][ch * 32 + q * 8];
        #pragma unroll
        for (int ct = 0; ct < 3; ++ct) {
            frag_h bF = *(const frag_h*)(W2T + (size_t)(ct * 16 + lb) * 128 + ch * 32 + q * 8);
            a2[ct] = __builtin_amdgcn_mfma_f32_16x16x32_f16(zF, bF, a2[ct], 0, 0, 0);
        }
    }

    // ---- log_softmax over 40 cols; lane holds cols {lb, 16+lb, 32+lb} ----
    float lg[3][4];
    #pragma unroll
    for (int ct = 0; ct < 3; ++ct) {
        int col = ct * 16 + lb;
        bool valid = col < 40;
        float bb = valid ? b2[col] : -1e30f;
        #pragma unroll
        for (int rg = 0; rg < 4; ++rg)
            lg[ct][rg] = valid ? (a2[ct][rg] + bb) : -1e30f;
    }
    #pragma unroll
    for (int rg = 0; rg < 4; ++rg) {
        float mx = fmaxf(fmaxf(lg[0][rg], lg[1][rg]), lg[2][rg]);
        #pragma unroll
        for (int m = 1; m < 16; m <<= 1) mx = fmaxf(mx, __shfl_xor(mx, m, 64));
        float sm = __expf(lg[0][rg] - mx) + __expf(lg[1][rg] - mx) + __expf(lg[2][rg] - mx);
        #pragma unroll
        for (int m = 1; m < 16; m <<= 1) sm += __shfl_xor(sm, m, 64);
        float ls = mx + __logf(sm);
        int row = n0 + wv * 16 + q * 4 + rg;
        #pragma unroll
        for (int ct = 0; ct < 3; ++ct) {
            int col = ct * 16 + lb;
            if (col < 40) out[(size_t)row * 40 + col] = lg[ct][rg] - ls;
        }
    }
}

extern "C" void kernel_launch(void* const* d_in, const int* in_sizes, int n_in,
                              void* d_out, int out_size, void* d_ws, size_t ws_size,
                              hipStream_t stream) {
    const float* x  = (const float*)d_in[0];
    const int*   ei = (const int*)d_in[1];
    const float* Wm = (const float*)d_in[2];
    const float* bm = (const float*)d_in[3];
    const float* Wa = (const float*)d_in[4];
    const float* ba = (const float*)d_in[5];
    const float* W1 = (const float*)d_in[6];
    const float* b1 = (const float*)d_in[7];
    const float* W2 = (const float*)d_in[8];
    const float* b2 = (const float*)d_in[9];
    float* out = (float*)d_out;

    const int N = in_sizes[0] / XSTRIDE;   // 40000
    const int E = in_sizes[1] / 2;         // 480000
    const int NB = (N + 255) / 256;        // 157
    const size_t P = (size_t)N * 128;      // plane elements

    // workspace carve (16B-aligned)
    _Float16* Mb  = (_Float16*)d_ws;       // msg fp16
    _Float16* X   = Mb + P;                // x feats (reused as F2 for final)
    _Float16* S   = X + P;                 // aggr
    _Float16* F1  = S + P;                 // layer-1 out
    _Float16* WmT = F1 + P;                // 6*128*128
    _Float16* WaT = WmT + CW_M;            // 6*128*256
    _Float16* W1T = WaT + CW_A;            // 128*128
    _Float16* W2T = W1T + CW_1;            // 48*128
    int* cnt   = (int*)(W2T + CW_2);       // N   (memset together with fc)
    int* fc    = cnt + N;                  // N
    int* offs  = fc + N;                   // N+1
    int* csr   = offs + N + 1;             // E
    int* bsums = csr + E;                  // NB

    // ---- pre-convert (1 kernel for all weights) ----
    conv_all<<<(CW_M + CW_A + CW_1 + CW_2 + 255) / 256, 256, 0, stream>>>(
        Wm, Wa, W1, W2, WmT, WaT, W1T, W2T);
    conv_x<<<(N * 128 + 255) / 256, 256, 0, stream>>>(x, X, N * 128);

    // ---- CSR build (single memset covers cnt + fc) ----
    hipMemsetAsync(cnt, 0, (size_t)2 * N * sizeof(int), stream);
    count_kernel<<<(E + 255) / 256, 256, 0, stream>>>(ei, E, cnt);
    scanA<<<NB, 256, 0, stream>>>(cnt, N, bsums);
    scanB<<<1, 256, 0, stream>>>(bsums, NB);
    scanC<<<NB, 256, 0, stream>>>(cnt, N, bsums, offs);
    fill_kernel<<<(E + 255) / 256, 256, 0, stream>>>(ei, E, offs, fc, csr);

    const int gblk = N / 64;               // 625
    for (int l = 0; l < 2; ++l) {
        const _Float16* fp = (l == 0) ? X : F1;
        _Float16* o = (l == 0) ? F1 : X;   // layer-2 output aliases X (becomes F2)

        gemm_mfma<128, false><<<gblk, 256, 0, stream>>>(
            x, fp, nullptr,
            WmT + (size_t)l * 3 * 128 * 128, bm + (size_t)l * 4 * 128, Mb);
        agg_kernel<<<(N + 7) / 8, 256, 0, stream>>>(csr, offs, Mb, S, N);
        gemm_mfma<256, true><<<gblk, 256, 0, stream>>>(
            x, fp, S,
            WaT + (size_t)l * 3 * 128 * 256, ba + (size_t)l * 4 * 128, o);
    }

    final_mfma<<<N / 64, 256, 0, stream>>>(X, W1T, b1, W2T, b2, out);
}

// Round 10
// 295.922 us; speedup vs baseline: 1.2497x; 1.0391x over previous
//
#include <hip/hip_runtime.h>
#include <hip/hip_fp16.h>

#define RN 4
#define XSTRIDE 132   // R + DIN

typedef float    frag_cd __attribute__((ext_vector_type(4)));
typedef _Float16 frag_h  __attribute__((ext_vector_type(8)));

#define CW_M  (6 * 128 * 128)
#define CW_A  (6 * 128 * 256)
#define CW_1  (128 * 128)
#define CW_2  (48 * 128)
#define CW_TOT (CW_M + CW_A + CW_1 + CW_2)

// ---------------- merged prep: weight converts + x convert + degree count ---
// section 1: weights -> transposed fp16 planes
// section 2: x feats -> fp16 plane [N][128], 8 elements/thread
// section 3: in-degree count (atomics into cnt, pre-zeroed)
__global__ void prep_kernel(
    const float* __restrict__ Wm, const float* __restrict__ Wa,
    const float* __restrict__ W1, const float* __restrict__ W2,
    _Float16* __restrict__ WmT, _Float16* __restrict__ WaT,
    _Float16* __restrict__ W1T, _Float16* __restrict__ W2T,
    const float* __restrict__ x, _Float16* __restrict__ X,
    const int* __restrict__ ei, int* __restrict__ cnt, int N, int E)
{
    int id = blockIdx.x * 256 + threadIdx.x;
    if (id < CW_M) {
        const int K = 128;
        int per = K * 128;
        int lr = id / per;  int l = lr / 3, r = lr - l * 3;
        int rem = id - lr * per;
        int k = rem >> 7, col = rem & 127;
        WmT[((size_t)lr * 128 + col) * K + k] =
            (_Float16)Wm[(((size_t)l * 4 + r) * K + k) * 128 + col];
        return;
    }
    id -= CW_M;
    if (id < CW_A) {
        const int K = 256;
        int per = K * 128;
        int lr = id / per;  int l = lr / 3, r = lr - l * 3;
        int rem = id - lr * per;
        int k = rem >> 7, col = rem & 127;
        WaT[((size_t)lr * 128 + col) * K + k] =
            (_Float16)Wa[(((size_t)l * 4 + r) * K + k) * 128 + col];
        return;
    }
    id -= CW_A;
    if (id < CW_1) {
        int col = id >> 7, k = id & 127;
        W1T[id] = (_Float16)W1[k * 128 + col];
        return;
    }
    id -= CW_1;
    if (id < CW_2) {
        int col = id >> 7, k = id & 127;
        W2T[id] = (_Float16)((col < 40) ? W2[k * 40 + col] : 0.0f);
        return;
    }
    id -= CW_2;
    if (id < N * 16) {              // x convert: 8 floats -> 8 halves
        int n = id >> 4, g = id & 15;
        const float4* src = (const float4*)(x + (size_t)n * XSTRIDE + RN + g * 8);
        float4 f0 = src[0], f1 = src[1];
        __half2 h0 = __float22half2_rn(make_float2(f0.x, f0.y));
        __half2 h1 = __float22half2_rn(make_float2(f0.z, f0.w));
        __half2 h2 = __float22half2_rn(make_float2(f1.x, f1.y));
        __half2 h3 = __float22half2_rn(make_float2(f1.z, f1.w));
        uint4 st; st.x = *(uint*)&h0; st.y = *(uint*)&h1;
        st.z = *(uint*)&h2; st.w = *(uint*)&h3;
        ((uint4*)X)[(size_t)n * 16 + g] = st;
        return;
    }
    id -= N * 16;
    if (id < E) atomicAdd(&cnt[ei[E + id]], 1);
}

// ---------------- CSR scans ------------------------------------------------
__global__ void scanA(const int* __restrict__ cnt, int N, int* __restrict__ bsums) {
    __shared__ int s[256];
    int t = threadIdx.x, n = blockIdx.x * 256 + t;
    s[t] = (n < N) ? cnt[n] : 0;
    __syncthreads();
    for (int off = 128; off > 0; off >>= 1) {
        if (t < off) s[t] += s[t + off];
        __syncthreads();
    }
    if (t == 0) bsums[blockIdx.x] = s[0];
}

// scanC with inlined scanB: each block reduces bsums[0..bid) itself.
__global__ void scanC(const int* __restrict__ cnt, int N, int nb,
                      const int* __restrict__ bsums, int* __restrict__ offs) {
    __shared__ int s[256];
    __shared__ int basebuf[256];
    int t = threadIdx.x, n = blockIdx.x * 256 + t;
    int bid = blockIdx.x;
    basebuf[t] = (t < bid && t < nb) ? bsums[t] : 0;
    __syncthreads();
    for (int off = 128; off > 0; off >>= 1) {
        if (t < off) basebuf[t] += basebuf[t + off];
        __syncthreads();
    }
    int base = basebuf[0];
    int v = (n < N) ? cnt[n] : 0;
    s[t] = v; __syncthreads();
    for (int off = 1; off < 256; off <<= 1) {
        int add = (t >= off) ? s[t - off] : 0;
        __syncthreads();
        s[t] += add;
        __syncthreads();
    }
    if (n < N) {
        offs[n] = base + s[t] - v;
        if (n == N - 1) offs[N] = base + s[t];
    }
}

__global__ void fill_kernel(const int* __restrict__ ei, int E,
                            const int* __restrict__ offs, int* __restrict__ fc,
                            int* __restrict__ csr) {
    int e = blockIdx.x * 256 + threadIdx.x;
    if (e < E) {
        int dst = ei[E + e];
        int p = offs[dst] + atomicAdd(&fc[dst], 1);
        csr[p] = ei[e];
    }
}

// ---------------- aggregate: mean over in-edges of Mb (fp16) ---------------
// 16 lanes per node (lane = 16-B row segment), 4 nodes/wave, 16 nodes/block;
// 4-edge unroll -> 4 independent uint4 loads in flight per lane.
__global__ __launch_bounds__(256) void agg_kernel(
    const int* __restrict__ csr, const int* __restrict__ offs,
    const _Float16* __restrict__ Mb, _Float16* __restrict__ S, int N)
{
    int node = blockIdx.x * 16 + (threadIdx.x >> 4);
    int lane = threadIdx.x & 15;
    if (node >= N) return;
    int lo = offs[node], hi = offs[node + 1];
    const uint4* M4 = (const uint4*)Mb;     // row = 16 x uint4
    float a[8];
    #pragma unroll
    for (int i = 0; i < 8; ++i) a[i] = 0.0f;
    int e = lo;
    for (; e + 3 < hi; e += 4) {
        #pragma unroll
        for (int j = 0; j < 4; ++j) {
            uint4 u = M4[(size_t)csr[e + j] * 16 + lane];
            float2 f0 = __half22float2(*(const __half2*)&u.x);
            float2 f1 = __half22float2(*(const __half2*)&u.y);
            float2 f2 = __half22float2(*(const __half2*)&u.z);
            float2 f3 = __half22float2(*(const __half2*)&u.w);
            a[0] += f0.x; a[1] += f0.y; a[2] += f1.x; a[3] += f1.y;
            a[4] += f2.x; a[5] += f2.y; a[6] += f3.x; a[7] += f3.y;
        }
    }
    for (; e < hi; ++e) {
        uint4 u = M4[(size_t)csr[e] * 16 + lane];
        float2 f0 = __half22float2(*(const __half2*)&u.x);
        float2 f1 = __half22float2(*(const __half2*)&u.y);
        float2 f2 = __half22float2(*(const __half2*)&u.z);
        float2 f3 = __half22float2(*(const __half2*)&u.w);
        a[0] += f0.x; a[1] += f0.y; a[2] += f1.x; a[3] += f1.y;
        a[4] += f2.x; a[5] += f2.y; a[6] += f3.x; a[7] += f3.y;
    }
    float inv = (hi > lo) ? 1.0f / (float)(hi - lo) : 0.0f;
    __half2 h0 = __float22half2_rn(make_float2(a[0] * inv, a[1] * inv));
    __half2 h1 = __float22half2_rn(make_float2(a[2] * inv, a[3] * inv));
    __half2 h2 = __float22half2_rn(make_float2(a[4] * inv, a[5] * inv));
    __half2 h3 = __float22half2_rn(make_float2(a[6] * inv, a[7] * inv));
    uint4 st; st.x = *(uint*)&h0; st.y = *(uint*)&h1;
    st.z = *(uint*)&h2; st.w = *(uint*)&h3;
    ((uint4*)S)[(size_t)node * 16 + lane] = st;
}

// ---------------- MFMA role-weighted GEMM, fp16, 64-row tile ---------------
// out = relu( sum_r c_r (v @ W_r + b_r) ), opt row-norm.
// Single accumulator via role-scaled A (one v_pk_mul_f16 splat per frag).
// KV=128: FULL K prefetch (all 4 chunks' 40 frags up front).
// KV=256: triple-buffered prefetch (chunks ch+1, ch+2 in flight).
template<int KV, bool NORM>
__global__ __launch_bounds__(256) void gemm_mfma(
    const float* __restrict__ x,
    const _Float16* __restrict__ Fp,               // [N][128]
    const _Float16* __restrict__ Sp,               // KV==256 only
    const _Float16* __restrict__ W,                // [3][128][KV]
    const float* __restrict__ bias,                // [4][128]
    _Float16* __restrict__ out)                    // [N][128]
{
    __shared__ float cc[64][3];
    __shared__ float red[64][4];

    const int tid = threadIdx.x;
    const int n0 = blockIdx.x * 64;
    const int lane = tid & 63;
    const int wv = tid >> 6;
    const int q = lane >> 4;
    const int lb = lane & 15;
    const int w32 = wv * 32;

    if (tid < 64) {
        const float* xr = x + (size_t)(n0 + tid) * XSTRIDE;
        cc[tid][0] = 2.0f * xr[0];
        cc[tid][1] = xr[1];
        cc[tid][2] = xr[2];
    }
    __syncthreads();

    _Float16 ch16[4][3];
    #pragma unroll
    for (int nt = 0; nt < 4; ++nt)
        #pragma unroll
        for (int r = 0; r < 3; ++r)
            ch16[nt][r] = (_Float16)cc[nt * 16 + lb][r];

    frag_cd acc[4][2];
    #pragma unroll
    for (int nt = 0; nt < 4; ++nt)
        #pragma unroll
        for (int ct = 0; ct < 2; ++ct)
            acc[nt][ct] = (frag_cd){0.f, 0.f, 0.f, 0.f};

    size_t wrow[3][2];
    #pragma unroll
    for (int r = 0; r < 3; ++r)
        #pragma unroll
        for (int ct = 0; ct < 2; ++ct)
            wrow[r][ct] = ((size_t)(r * 128 + w32 + ct * 16 + lb)) * KV + q * 8;

    size_t arow[4];
    #pragma unroll
    for (int nt = 0; nt < 4; ++nt)
        arow[nt] = (size_t)(n0 + nt * 16 + lb) * 128 + q * 8;

    if (KV == 128) {
        // full prefetch: 4 chunks x (4 A + 6 B) frags
        frag_h aF[4][4], bF[4][6];
        #pragma unroll
        for (int c = 0; c < 4; ++c) {
            #pragma unroll
            for (int nt = 0; nt < 4; ++nt)
                aF[c][nt] = *(const frag_h*)(Fp + arow[nt] + c * 32);
            #pragma unroll
            for (int r = 0; r < 3; ++r)
                #pragma unroll
                for (int ct = 0; ct < 2; ++ct)
                    bF[c][r * 2 + ct] = *(const frag_h*)(W + wrow[r][ct] + c * 32);
        }
        #pragma unroll
        for (int c = 0; c < 4; ++c)
            #pragma unroll
            for (int r = 0; r < 3; ++r)
                #pragma unroll
                for (int nt = 0; nt < 4; ++nt) {
                    frag_h sa = aF[c][nt] * ch16[nt][r];
                    #pragma unroll
                    for (int ct = 0; ct < 2; ++ct)
                        acc[nt][ct] = __builtin_amdgcn_mfma_f32_16x16x32_f16(
                            sa, bF[c][r * 2 + ct], acc[nt][ct], 0, 0, 0);
                }
    } else {
        const int NCH = KV / 32;
        frag_h aF[3][4], bF[3][6];
        auto loadChunk = [&](int c, int buf) {
            const _Float16* ap; int kofs;
            if (c < 4) { ap = Fp; kofs = c * 32; }
            else       { ap = Sp; kofs = (c - 4) * 32; }
            #pragma unroll
            for (int nt = 0; nt < 4; ++nt)
                aF[buf][nt] = *(const frag_h*)(ap + arow[nt] + kofs);
            #pragma unroll
            for (int r = 0; r < 3; ++r)
                #pragma unroll
                for (int ct = 0; ct < 2; ++ct)
                    bF[buf][r * 2 + ct] = *(const frag_h*)(W + wrow[r][ct] + c * 32);
        };
        loadChunk(0, 0);
        loadChunk(1, 1);
        #pragma unroll
        for (int ch = 0; ch < NCH; ++ch) {
            if (ch + 2 < NCH) loadChunk(ch + 2, (ch + 2) % 3);
            const int cur = ch % 3;
            #pragma unroll
            for (int r = 0; r < 3; ++r)
                #pragma unroll
                for (int nt = 0; nt < 4; ++nt) {
                    frag_h sa = aF[cur][nt] * ch16[nt][r];
                    #pragma unroll
                    for (int ct = 0; ct < 2; ++ct)
                        acc[nt][ct] = __builtin_amdgcn_mfma_f32_16x16x32_f16(
                            sa, bF[cur][r * 2 + ct], acc[nt][ct], 0, 0, 0);
                }
        }
    }

    // ---- epilogue: + sum_r c_r b_r, relu; C/D: col=lane&15, row=q*4+reg ----
    float vv[4][2][4];
    #pragma unroll
    for (int ct = 0; ct < 2; ++ct) {
        int col = w32 + ct * 16 + lb;
        float b0 = bias[col], b1 = bias[128 + col], b2 = bias[256 + col];
        #pragma unroll
        for (int nt = 0; nt < 4; ++nt) {
            #pragma unroll
            for (int rg = 0; rg < 4; ++rg) {
                int row = nt * 16 + q * 4 + rg;
                float v = acc[nt][ct][rg]
                        + cc[row][0] * b0 + cc[row][1] * b1 + cc[row][2] * b2;
                vv[nt][ct][rg] = fmaxf(v, 0.0f);
            }
        }
    }

    if (NORM) {
        #pragma unroll
        for (int nt = 0; nt < 4; ++nt) {
            #pragma unroll
            for (int rg = 0; rg < 4; ++rg) {
                float ss = vv[nt][0][rg] * vv[nt][0][rg] + vv[nt][1][rg] * vv[nt][1][rg];
                #pragma unroll
                for (int m = 1; m < 16; m <<= 1) ss += __shfl_xor(ss, m, 64);
                if (lb == 0) red[nt * 16 + q * 4 + rg][wv] = ss;
            }
        }
        __syncthreads();
        #pragma unroll
        for (int nt = 0; nt < 4; ++nt) {
            #pragma unroll
            for (int rg = 0; rg < 4; ++rg) {
                int row = nt * 16 + q * 4 + rg;
                float t = red[row][0] + red[row][1] + red[row][2] + red[row][3];
                float inv = 1.0f / fmaxf(sqrtf(t), 1e-12f);
                #pragma unroll
                for (int ct = 0; ct < 2; ++ct) {
                    int col = w32 + ct * 16 + lb;
                    out[(size_t)(n0 + row) * 128 + col] = (_Float16)(vv[nt][ct][rg] * inv);
                }
            }
        }
    } else {
        #pragma unroll
        for (int nt = 0; nt < 4; ++nt)
            #pragma unroll
            for (int ct = 0; ct < 2; ++ct)
                #pragma unroll
                for (int rg = 0; rg < 4; ++rg) {
                    int row = nt * 16 + q * 4 + rg;
                    int col = w32 + ct * 16 + lb;
                    out[(size_t)(n0 + row) * 128 + col] = (_Float16)vv[nt][ct][rg];
                }
    }
}

// ---------------- final: z=F@W1+b1; logits=z@W2+b2; log_softmax (MFMA) ------
__global__ __launch_bounds__(256) void final_mfma(
    const _Float16* __restrict__ F2,               // [N][128]
    const _Float16* __restrict__ W1T,              // [128][128] ([col][k])
    const float* __restrict__ b1,
    const _Float16* __restrict__ W2T,              // [48][128] zero-padded
    const float* __restrict__ b2,
    float* __restrict__ out)                       // N x 40
{
    __shared__ _Float16 Z[64][136];

    const int tid = threadIdx.x;
    const int n0 = blockIdx.x * 64;
    const int lane = tid & 63;
    const int wv = tid >> 6;
    const int q = lane >> 4;
    const int lb = lane & 15;
    const int w32 = wv * 32;

    frag_cd acc[4][2];
    #pragma unroll
    for (int nt = 0; nt < 4; ++nt)
        #pragma unroll
        for (int ct = 0; ct < 2; ++ct) acc[nt][ct] = (frag_cd){0.f, 0.f, 0.f, 0.f};

    #pragma unroll
    for (int ch = 0; ch < 4; ++ch) {
        frag_h aF[4];
        #pragma unroll
        for (int nt = 0; nt < 4; ++nt)
            aF[nt] = *(const frag_h*)(F2 + (size_t)(n0 + nt * 16 + lb) * 128 + ch * 32 + q * 8);
        #pragma unroll
        for (int ct = 0; ct < 2; ++ct) {
            frag_h bF = *(const frag_h*)(W1T + (size_t)(w32 + ct * 16 + lb) * 128 + ch * 32 + q * 8);
            #pragma unroll
            for (int nt = 0; nt < 4; ++nt)
                acc[nt][ct] = __builtin_amdgcn_mfma_f32_16x16x32_f16(aF[nt], bF, acc[nt][ct], 0, 0, 0);
        }
    }
    #pragma unroll
    for (int ct = 0; ct < 2; ++ct) {
        int col = w32 + ct * 16 + lb;
        float bb = b1[col];
        #pragma unroll
        for (int nt = 0; nt < 4; ++nt)
            #pragma unroll
            for (int rg = 0; rg < 4; ++rg)
                Z[nt * 16 + q * 4 + rg][col] = (_Float16)(acc[nt][ct][rg] + bb);
    }
    __syncthreads();

    frag_cd a2[3];
    #pragma unroll
    for (int ct = 0; ct < 3; ++ct) a2[ct] = (frag_cd){0.f, 0.f, 0.f, 0.f};
    #pragma unroll
    for (int ch = 0; ch < 4; ++ch) {
        frag_h zF = *(const frag_h*)&Z[wv * 16 + lb][ch * 32 + q * 8];
        #pragma unroll
        for (int ct = 0; ct < 3; ++ct) {
            frag_h bF = *(const frag_h*)(W2T + (size_t)(ct * 16 + lb) * 128 + ch * 32 + q * 8);
            a2[ct] = __builtin_amdgcn_mfma_f32_16x16x32_f16(zF, bF, a2[ct], 0, 0, 0);
        }
    }

    float lg[3][4];
    #pragma unroll
    for (int ct = 0; ct < 3; ++ct) {
        int col = ct * 16 + lb;
        bool valid = col < 40;
        float bb = valid ? b2[col] : -1e30f;
        #pragma unroll
        for (int rg = 0; rg < 4; ++rg)
            lg[ct][rg] = valid ? (a2[ct][rg] + bb) : -1e30f;
    }
    #pragma unroll
    for (int rg = 0; rg < 4; ++rg) {
        float mx = fmaxf(fmaxf(lg[0][rg], lg[1][rg]), lg[2][rg]);
        #pragma unroll
        for (int m = 1; m < 16; m <<= 1) mx = fmaxf(mx, __shfl_xor(mx, m, 64));
        float sm = __expf(lg[0][rg] - mx) + __expf(lg[1][rg] - mx) + __expf(lg[2][rg] - mx);
        #pragma unroll
        for (int m = 1; m < 16; m <<= 1) sm += __shfl_xor(sm, m, 64);
        float ls = mx + __logf(sm);
        int row = n0 + wv * 16 + q * 4 + rg;
        #pragma unroll
        for (int ct = 0; ct < 3; ++ct) {
            int col = ct * 16 + lb;
            if (col < 40) out[(size_t)row * 40 + col] = lg[ct][rg] - ls;
        }
    }
}

extern "C" void kernel_launch(void* const* d_in, const int* in_sizes, int n_in,
                              void* d_out, int out_size, void* d_ws, size_t ws_size,
                              hipStream_t stream) {
    const float* x  = (const float*)d_in[0];
    const int*   ei = (const int*)d_in[1];
    const float* Wm = (const float*)d_in[2];
    const float* bm = (const float*)d_in[3];
    const float* Wa = (const float*)d_in[4];
    const float* ba = (const float*)d_in[5];
    const float* W1 = (const float*)d_in[6];
    const float* b1 = (const float*)d_in[7];
    const float* W2 = (const float*)d_in[8];
    const float* b2 = (const float*)d_in[9];
    float* out = (float*)d_out;

    const int N = in_sizes[0] / XSTRIDE;   // 40000
    const int E = in_sizes[1] / 2;         // 480000
    const int NB = (N + 255) / 256;        // 157
    const size_t P = (size_t)N * 128;      // plane elements

    // workspace carve (16B-aligned)
    _Float16* Mb  = (_Float16*)d_ws;       // msg fp16
    _Float16* X   = Mb + P;                // x feats (aliased as layer-2 out F2)
    _Float16* S   = X + P;                 // aggr
    _Float16* F1  = S + P;                 // layer-1 out
    _Float16* WmT = F1 + P;
    _Float16* WaT = WmT + CW_M;
    _Float16* W1T = WaT + CW_A;
    _Float16* W2T = W1T + CW_1;
    int* cnt   = (int*)(W2T + CW_2);       // N (memset together with fc)
    int* fc    = cnt + N;                  // N
    int* offs  = fc + N;                   // N+1
    int* csr   = offs + N + 1;             // E
    int* bsums = csr + E;                  // NB

    // ---- prep: zero counters, then merged convert+count ----
    hipMemsetAsync(cnt, 0, (size_t)2 * N * sizeof(int), stream);
    const int prep_total = CW_TOT + N * 16 + E;
    prep_kernel<<<(prep_total + 255) / 256, 256, 0, stream>>>(
        Wm, Wa, W1, W2, WmT, WaT, W1T, W2T, x, X, ei, cnt, N, E);

    // ---- CSR: scanA -> scanC(inline scanB) -> fill ----
    scanA<<<NB, 256, 0, stream>>>(cnt, N, bsums);
    scanC<<<NB, 256, 0, stream>>>(cnt, N, NB, bsums, offs);
    fill_kernel<<<(E + 255) / 256, 256, 0, stream>>>(ei, E, offs, fc, csr);

    const int gblk = N / 64;               // 625
    for (int l = 0; l < 2; ++l) {
        const _Float16* fp = (l == 0) ? X : F1;
        _Float16* o = (l == 0) ? F1 : X;   // layer-2 output aliases X (becomes F2)

        gemm_mfma<128, false><<<gblk, 256, 0, stream>>>(
            x, fp, nullptr,
            WmT + (size_t)l * 3 * 128 * 128, bm + (size_t)l * 4 * 128, Mb);
        agg_kernel<<<(N + 15) / 16, 256, 0, stream>>>(csr, offs, Mb, S, N);
        gemm_mfma<256, true><<<gblk, 256, 0, stream>>>(
            x, fp, S,
            WaT + (size_t)l * 3 * 128 * 256, ba + (size_t)l * 4 * 128, o);
    }

    final_mfma<<<N / 64, 256, 0, stream>>>(X, W1T, b1, W2T, b2, out);
}

// Round 11
// 281.000 us; speedup vs baseline: 1.3161x; 1.0531x over previous
//
#include <hip/hip_runtime.h>
#include <hip/hip_fp16.h>

#define RN 4
#define XSTRIDE 132   // R + DIN

typedef float    frag_cd __attribute__((ext_vector_type(4)));
typedef _Float16 frag_h  __attribute__((ext_vector_type(8)));

#define CW_M  (6 * 128 * 128)
#define CW_A  (6 * 128 * 256)
#define CW_1  (128 * 128)
#define CW_2  (48 * 128)
#define CW_TOT (CW_M + CW_A + CW_1 + CW_2)

// ---------------- merged prep: weight converts + x convert + degree count ---
__global__ void prep_kernel(
    const float* __restrict__ Wm, const float* __restrict__ Wa,
    const float* __restrict__ W1, const float* __restrict__ W2,
    _Float16* __restrict__ WmT, _Float16* __restrict__ WaT,
    _Float16* __restrict__ W1T, _Float16* __restrict__ W2T,
    const float* __restrict__ x, _Float16* __restrict__ X,
    const int* __restrict__ ei, int* __restrict__ cnt, int N, int E)
{
    int id = blockIdx.x * 256 + threadIdx.x;
    if (id < CW_M) {
        const int K = 128;
        int per = K * 128;
        int lr = id / per;  int l = lr / 3, r = lr - l * 3;
        int rem = id - lr * per;
        int k = rem >> 7, col = rem & 127;
        WmT[((size_t)lr * 128 + col) * K + k] =
            (_Float16)Wm[(((size_t)l * 4 + r) * K + k) * 128 + col];
        return;
    }
    id -= CW_M;
    if (id < CW_A) {
        const int K = 256;
        int per = K * 128;
        int lr = id / per;  int l = lr / 3, r = lr - l * 3;
        int rem = id - lr * per;
        int k = rem >> 7, col = rem & 127;
        WaT[((size_t)lr * 128 + col) * K + k] =
            (_Float16)Wa[(((size_t)l * 4 + r) * K + k) * 128 + col];
        return;
    }
    id -= CW_A;
    if (id < CW_1) {
        int col = id >> 7, k = id & 127;
        W1T[id] = (_Float16)W1[k * 128 + col];
        return;
    }
    id -= CW_1;
    if (id < CW_2) {
        int col = id >> 7, k = id & 127;
        W2T[id] = (_Float16)((col < 40) ? W2[k * 40 + col] : 0.0f);
        return;
    }
    id -= CW_2;
    if (id < N * 16) {              // x convert: 8 floats -> 8 halves
        int n = id >> 4, g = id & 15;
        const float4* src = (const float4*)(x + (size_t)n * XSTRIDE + RN + g * 8);
        float4 f0 = src[0], f1 = src[1];
        __half2 h0 = __float22half2_rn(make_float2(f0.x, f0.y));
        __half2 h1 = __float22half2_rn(make_float2(f0.z, f0.w));
        __half2 h2 = __float22half2_rn(make_float2(f1.x, f1.y));
        __half2 h3 = __float22half2_rn(make_float2(f1.z, f1.w));
        uint4 st; st.x = *(uint*)&h0; st.y = *(uint*)&h1;
        st.z = *(uint*)&h2; st.w = *(uint*)&h3;
        ((uint4*)X)[(size_t)n * 16 + g] = st;
        return;
    }
    id -= N * 16;
    if (id < E) atomicAdd(&cnt[ei[E + id]], 1);
}

// ---------------- CSR scans ------------------------------------------------
__global__ void scanA(const int* __restrict__ cnt, int N, int* __restrict__ bsums) {
    __shared__ int s[256];
    int t = threadIdx.x, n = blockIdx.x * 256 + t;
    s[t] = (n < N) ? cnt[n] : 0;
    __syncthreads();
    for (int off = 128; off > 0; off >>= 1) {
        if (t < off) s[t] += s[t + off];
        __syncthreads();
    }
    if (t == 0) bsums[blockIdx.x] = s[0];
}

__global__ void scanC(const int* __restrict__ cnt, int N, int nb,
                      const int* __restrict__ bsums, int* __restrict__ offs) {
    __shared__ int s[256];
    __shared__ int basebuf[256];
    int t = threadIdx.x, n = blockIdx.x * 256 + t;
    int bid = blockIdx.x;
    basebuf[t] = (t < bid && t < nb) ? bsums[t] : 0;
    __syncthreads();
    for (int off = 128; off > 0; off >>= 1) {
        if (t < off) basebuf[t] += basebuf[t + off];
        __syncthreads();
    }
    int base = basebuf[0];
    int v = (n < N) ? cnt[n] : 0;
    s[t] = v; __syncthreads();
    for (int off = 1; off < 256; off <<= 1) {
        int add = (t >= off) ? s[t - off] : 0;
        __syncthreads();
        s[t] += add;
        __syncthreads();
    }
    if (n < N) {
        offs[n] = base + s[t] - v;
        if (n == N - 1) offs[N] = base + s[t];
    }
}

__global__ void fill_kernel(const int* __restrict__ ei, int E,
                            const int* __restrict__ offs, int* __restrict__ fc,
                            int* __restrict__ csr) {
    int e = blockIdx.x * 256 + threadIdx.x;
    if (e < E) {
        int dst = ei[E + e];
        int p = offs[dst] + atomicAdd(&fc[dst], 1);
        csr[p] = ei[e];
    }
}

// ---------------- aggregate: mean over in-edges of Mb (fp16) ---------------
__global__ __launch_bounds__(256) void agg_kernel(
    const int* __restrict__ csr, const int* __restrict__ offs,
    const _Float16* __restrict__ Mb, _Float16* __restrict__ S, int N)
{
    int node = blockIdx.x * 16 + (threadIdx.x >> 4);
    int lane = threadIdx.x & 15;
    if (node >= N) return;
    int lo = offs[node], hi = offs[node + 1];
    const uint4* M4 = (const uint4*)Mb;     // row = 16 x uint4
    float a[8];
    #pragma unroll
    for (int i = 0; i < 8; ++i) a[i] = 0.0f;
    int e = lo;
    for (; e + 3 < hi; e += 4) {
        #pragma unroll
        for (int j = 0; j < 4; ++j) {
            uint4 u = M4[(size_t)csr[e + j] * 16 + lane];
            float2 f0 = __half22float2(*(const __half2*)&u.x);
            float2 f1 = __half22float2(*(const __half2*)&u.y);
            float2 f2 = __half22float2(*(const __half2*)&u.z);
            float2 f3 = __half22float2(*(const __half2*)&u.w);
            a[0] += f0.x; a[1] += f0.y; a[2] += f1.x; a[3] += f1.y;
            a[4] += f2.x; a[5] += f2.y; a[6] += f3.x; a[7] += f3.y;
        }
    }
    for (; e < hi; ++e) {
        uint4 u = M4[(size_t)csr[e] * 16 + lane];
        float2 f0 = __half22float2(*(const __half2*)&u.x);
        float2 f1 = __half22float2(*(const __half2*)&u.y);
        float2 f2 = __half22float2(*(const __half2*)&u.z);
        float2 f3 = __half22float2(*(const __half2*)&u.w);
        a[0] += f0.x; a[1] += f0.y; a[2] += f1.x; a[3] += f1.y;
        a[4] += f2.x; a[5] += f2.y; a[6] += f3.x; a[7] += f3.y;
    }
    float inv = (hi > lo) ? 1.0f / (float)(hi - lo) : 0.0f;
    __half2 h0 = __float22half2_rn(make_float2(a[0] * inv, a[1] * inv));
    __half2 h1 = __float22half2_rn(make_float2(a[2] * inv, a[3] * inv));
    __half2 h2 = __float22half2_rn(make_float2(a[4] * inv, a[5] * inv));
    __half2 h3 = __float22half2_rn(make_float2(a[6] * inv, a[7] * inv));
    uint4 st; st.x = *(uint*)&h0; st.y = *(uint*)&h1;
    st.z = *(uint*)&h2; st.w = *(uint*)&h3;
    ((uint4*)S)[(size_t)node * 16 + lane] = st;
}

// ---------------- layer-1 msg GEMM (KV=128, full prefetch) -----------------
// Mb = relu(sum_r c_r (X @ Wm_r + bm_r)); single acc via role-scaled A.
__global__ __launch_bounds__(256) void msg_kernel(
    const float* __restrict__ x,
    const _Float16* __restrict__ Fp,               // [N][128]
    const _Float16* __restrict__ W,                // [3][128][128]
    const float* __restrict__ bias,                // [4][128]
    _Float16* __restrict__ out)
{
    __shared__ float cc[64][3];

    const int tid = threadIdx.x;
    const int n0 = blockIdx.x * 64;
    const int lane = tid & 63;
    const int wv = tid >> 6;
    const int q = lane >> 4;
    const int lb = lane & 15;
    const int w32 = wv * 32;

    if (tid < 64) {
        const float* xr = x + (size_t)(n0 + tid) * XSTRIDE;
        cc[tid][0] = 2.0f * xr[0];
        cc[tid][1] = xr[1];
        cc[tid][2] = xr[2];
    }
    __syncthreads();

    _Float16 ch16[4][3];
    #pragma unroll
    for (int nt = 0; nt < 4; ++nt)
        #pragma unroll
        for (int r = 0; r < 3; ++r)
            ch16[nt][r] = (_Float16)cc[nt * 16 + lb][r];

    frag_cd acc[4][2];
    #pragma unroll
    for (int nt = 0; nt < 4; ++nt)
        #pragma unroll
        for (int ct = 0; ct < 2; ++ct)
            acc[nt][ct] = (frag_cd){0.f, 0.f, 0.f, 0.f};

    size_t wrow[3][2];
    #pragma unroll
    for (int r = 0; r < 3; ++r)
        #pragma unroll
        for (int ct = 0; ct < 2; ++ct)
            wrow[r][ct] = ((size_t)(r * 128 + w32 + ct * 16 + lb)) * 128 + q * 8;

    size_t arow[4];
    #pragma unroll
    for (int nt = 0; nt < 4; ++nt)
        arow[nt] = (size_t)(n0 + nt * 16 + lb) * 128 + q * 8;

    frag_h aF[4][4], bF[4][6];
    #pragma unroll
    for (int c = 0; c < 4; ++c) {
        #pragma unroll
        for (int nt = 0; nt < 4; ++nt)
            aF[c][nt] = *(const frag_h*)(Fp + arow[nt] + c * 32);
        #pragma unroll
        for (int r = 0; r < 3; ++r)
            #pragma unroll
            for (int ct = 0; ct < 2; ++ct)
                bF[c][r * 2 + ct] = *(const frag_h*)(W + wrow[r][ct] + c * 32);
    }
    #pragma unroll
    for (int c = 0; c < 4; ++c)
        #pragma unroll
        for (int r = 0; r < 3; ++r)
            #pragma unroll
            for (int nt = 0; nt < 4; ++nt) {
                frag_h sa = aF[c][nt] * ch16[nt][r];
                #pragma unroll
                for (int ct = 0; ct < 2; ++ct)
                    acc[nt][ct] = __builtin_amdgcn_mfma_f32_16x16x32_f16(
                        sa, bF[c][r * 2 + ct], acc[nt][ct], 0, 0, 0);
            }

    #pragma unroll
    for (int ct = 0; ct < 2; ++ct) {
        int col = w32 + ct * 16 + lb;
        float b0 = bias[col], b1 = bias[128 + col], b2 = bias[256 + col];
        #pragma unroll
        for (int nt = 0; nt < 4; ++nt)
            #pragma unroll
            for (int rg = 0; rg < 4; ++rg) {
                int row = nt * 16 + q * 4 + rg;
                float v = acc[nt][ct][rg]
                        + cc[row][0] * b0 + cc[row][1] * b1 + cc[row][2] * b2;
                out[(size_t)(n0 + row) * 128 + col] = (_Float16)fmaxf(v, 0.0f);
            }
    }
}

// ============ PHASE-A MACRO: role-weighted update GEMM (KV=256) ============
// Computes normalized, relu'd update for rows [n0,n0+64) into LDS Fs (fp16).
// Triple-buffered direct-global frag prefetch; single acc via role-scaled A.
#define UPDATE_PHASE_A(Fp, Sp, Wa_, ba_)                                      \
    _Float16 ch16[4][3];                                                      \
    _Pragma("unroll")                                                         \
    for (int nt = 0; nt < 4; ++nt)                                            \
        _Pragma("unroll")                                                     \
        for (int r = 0; r < 3; ++r)                                           \
            ch16[nt][r] = (_Float16)cc[nt * 16 + lb][r];                      \
    frag_cd acc[4][2];                                                        \
    _Pragma("unroll")                                                         \
    for (int nt = 0; nt < 4; ++nt)                                            \
        _Pragma("unroll")                                                     \
        for (int ct = 0; ct < 2; ++ct)                                        \
            acc[nt][ct] = (frag_cd){0.f, 0.f, 0.f, 0.f};                      \
    size_t wrow[3][2];                                                        \
    _Pragma("unroll")                                                         \
    for (int r = 0; r < 3; ++r)                                               \
        _Pragma("unroll")                                                     \
        for (int ct = 0; ct < 2; ++ct)                                        \
            wrow[r][ct] = ((size_t)(r * 128 + w32 + ct * 16 + lb)) * 256 + q * 8; \
    size_t arow[4];                                                           \
    _Pragma("unroll")                                                         \
    for (int nt = 0; nt < 4; ++nt)                                            \
        arow[nt] = (size_t)(n0 + nt * 16 + lb) * 128 + q * 8;                 \
    {                                                                         \
        frag_h aF[3][4], bF[3][6];                                            \
        auto loadChunk = [&](int c, int buf) {                                \
            const _Float16* ap; int kofs;                                     \
            if (c < 4) { ap = (Fp); kofs = c * 32; }                          \
            else       { ap = (Sp); kofs = (c - 4) * 32; }                    \
            _Pragma("unroll")                                                 \
            for (int nt = 0; nt < 4; ++nt)                                    \
                aF[buf][nt] = *(const frag_h*)(ap + arow[nt] + kofs);         \
            _Pragma("unroll")                                                 \
            for (int r = 0; r < 3; ++r)                                       \
                _Pragma("unroll")                                             \
                for (int ct = 0; ct < 2; ++ct)                                \
                    bF[buf][r * 2 + ct] = *(const frag_h*)((Wa_) + wrow[r][ct] + c * 32); \
        };                                                                    \
        loadChunk(0, 0);                                                      \
        loadChunk(1, 1);                                                      \
        _Pragma("unroll")                                                     \
        for (int ch = 0; ch < 8; ++ch) {                                      \
            if (ch + 2 < 8) loadChunk(ch + 2, (ch + 2) % 3);                  \
            const int cur = ch % 3;                                           \
            _Pragma("unroll")                                                 \
            for (int r = 0; r < 3; ++r)                                       \
                _Pragma("unroll")                                             \
                for (int nt = 0; nt < 4; ++nt) {                              \
                    frag_h sa = aF[cur][nt] * ch16[nt][r];                    \
                    _Pragma("unroll")                                         \
                    for (int ct = 0; ct < 2; ++ct)                            \
                        acc[nt][ct] = __builtin_amdgcn_mfma_f32_16x16x32_f16( \
                            sa, bF[cur][r * 2 + ct], acc[nt][ct], 0, 0, 0);   \
                }                                                             \
        }                                                                     \
    }                                                                         \
    float vv[4][2][4];                                                        \
    _Pragma("unroll")                                                         \
    for (int ct = 0; ct < 2; ++ct) {                                          \
        int col = w32 + ct * 16 + lb;                                         \
        float b0 = (ba_)[col], b1 = (ba_)[128 + col], b2 = (ba_)[256 + col];  \
        _Pragma("unroll")                                                     \
        for (int nt = 0; nt < 4; ++nt)                                        \
            _Pragma("unroll")                                                 \
            for (int rg = 0; rg < 4; ++rg) {                                  \
                int row = nt * 16 + q * 4 + rg;                               \
                float v = acc[nt][ct][rg]                                     \
                        + cc[row][0] * b0 + cc[row][1] * b1 + cc[row][2] * b2;\
                vv[nt][ct][rg] = fmaxf(v, 0.0f);                              \
            }                                                                 \
    }                                                                         \
    _Pragma("unroll")                                                         \
    for (int nt = 0; nt < 4; ++nt)                                            \
        _Pragma("unroll")                                                     \
        for (int rg = 0; rg < 4; ++rg) {                                      \
            float ss = vv[nt][0][rg] * vv[nt][0][rg] + vv[nt][1][rg] * vv[nt][1][rg]; \
            _Pragma("unroll")                                                 \
            for (int m = 1; m < 16; m <<= 1) ss += __shfl_xor(ss, m, 64);     \
            if (lb == 0) red[nt * 16 + q * 4 + rg][wv] = ss;                  \
        }                                                                     \
    __syncthreads();                                                          \
    _Pragma("unroll")                                                         \
    for (int nt = 0; nt < 4; ++nt)                                            \
        _Pragma("unroll")                                                     \
        for (int rg = 0; rg < 4; ++rg) {                                      \
            int row = nt * 16 + q * 4 + rg;                                   \
            float t = red[row][0] + red[row][1] + red[row][2] + red[row][3];  \
            float inv = 1.0f / fmaxf(sqrtf(t), 1e-12f);                       \
            _Pragma("unroll")                                                 \
            for (int ct = 0; ct < 2; ++ct)                                    \
                Fs[row][w32 + ct * 16 + lb] = (_Float16)(vv[nt][ct][rg] * inv); \
        }                                                                     \
    __syncthreads();

// ---------------- fused: layer update (norm) + next-layer msg --------------
// Phase A: F_next rows -> LDS Fs + global F1 (vectorized).
// Phase B: Mb = relu(sum_r c_r (Fs @ Wm2_r + bm2_r)) with A from LDS.
__global__ __launch_bounds__(256) void fused_upd_msg(
    const float* __restrict__ x,
    const _Float16* __restrict__ Fp, const _Float16* __restrict__ Sp,
    const _Float16* __restrict__ Wa_, const float* __restrict__ ba_,
    const _Float16* __restrict__ Wm2, const float* __restrict__ bm2,
    _Float16* __restrict__ F1, _Float16* __restrict__ Mb)
{
    __shared__ float cc[64][3];
    __shared__ float red[64][4];
    __shared__ _Float16 Fs[64][136];

    const int tid = threadIdx.x;
    const int n0 = blockIdx.x * 64;
    const int lane = tid & 63;
    const int wv = tid >> 6;
    const int q = lane >> 4;
    const int lb = lane & 15;
    const int w32 = wv * 32;

    if (tid < 64) {
        const float* xr = x + (size_t)(n0 + tid) * XSTRIDE;
        cc[tid][0] = 2.0f * xr[0];
        cc[tid][1] = xr[1];
        cc[tid][2] = xr[2];
    }
    __syncthreads();

    UPDATE_PHASE_A(Fp, Sp, Wa_, ba_)

    // write F1 global, coalesced 16-B stores from LDS
    #pragma unroll
    for (int i = 0; i < 4; ++i) {
        int idx = i * 256 + tid;             // 0..1023
        int row = idx >> 4, g = idx & 15;
        ((uint4*)F1)[(size_t)(n0 + row) * 16 + g] = *(const uint4*)&Fs[row][g * 8];
    }

    // ---- Phase B: msg GEMM, A from LDS ----
    frag_cd a2[4][2];
    #pragma unroll
    for (int nt = 0; nt < 4; ++nt)
        #pragma unroll
        for (int ct = 0; ct < 2; ++ct)
            a2[nt][ct] = (frag_cd){0.f, 0.f, 0.f, 0.f};

    frag_h bB[4][6];
    #pragma unroll
    for (int c = 0; c < 4; ++c)
        #pragma unroll
        for (int r = 0; r < 3; ++r)
            #pragma unroll
            for (int ct = 0; ct < 2; ++ct)
                bB[c][r * 2 + ct] = *(const frag_h*)(
                    Wm2 + ((size_t)(r * 128 + w32 + ct * 16 + lb)) * 128 + c * 32 + q * 8);

    #pragma unroll
    for (int c = 0; c < 4; ++c) {
        frag_h aM[4];
        #pragma unroll
        for (int nt = 0; nt < 4; ++nt)
            aM[nt] = *(const frag_h*)&Fs[nt * 16 + lb][c * 32 + q * 8];
        #pragma unroll
        for (int r = 0; r < 3; ++r)
            #pragma unroll
            for (int nt = 0; nt < 4; ++nt) {
                frag_h sa = aM[nt] * ch16[nt][r];
                #pragma unroll
                for (int ct = 0; ct < 2; ++ct)
                    a2[nt][ct] = __builtin_amdgcn_mfma_f32_16x16x32_f16(
                        sa, bB[c][r * 2 + ct], a2[nt][ct], 0, 0, 0);
            }
    }

    #pragma unroll
    for (int ct = 0; ct < 2; ++ct) {
        int col = w32 + ct * 16 + lb;
        float b0 = bm2[col], b1 = bm2[128 + col], b2 = bm2[256 + col];
        #pragma unroll
        for (int nt = 0; nt < 4; ++nt)
            #pragma unroll
            for (int rg = 0; rg < 4; ++rg) {
                int row = nt * 16 + q * 4 + rg;
                float v = a2[nt][ct][rg]
                        + cc[row][0] * b0 + cc[row][1] * b1 + cc[row][2] * b2;
                Mb[(size_t)(n0 + row) * 128 + col] = (_Float16)fmaxf(v, 0.0f);
            }
    }
}

// ---------------- fused: layer-2 update (norm) + final MLP + log_softmax ----
// Phase A: F2 rows -> LDS only (never written to global).
// Phase B: z = F2@W1 + b1 -> LDS Z.  Phase C: logits=z@W2+b2, log_softmax.
__global__ __launch_bounds__(256) void fused_upd_final(
    const float* __restrict__ x,
    const _Float16* __restrict__ Fp, const _Float16* __restrict__ Sp,
    const _Float16* __restrict__ Wa_, const float* __restrict__ ba_,
    const _Float16* __restrict__ W1T, const float* __restrict__ b1,
    const _Float16* __restrict__ W2T, const float* __restrict__ b2,
    float* __restrict__ out)
{
    __shared__ float cc[64][3];
    __shared__ float red[64][4];
    __shared__ _Float16 Fs[64][136];
    __shared__ _Float16 Z[64][136];

    const int tid = threadIdx.x;
    const int n0 = blockIdx.x * 64;
    const int lane = tid & 63;
    const int wv = tid >> 6;
    const int q = lane >> 4;
    const int lb = lane & 15;
    const int w32 = wv * 32;

    if (tid < 64) {
        const float* xr = x + (size_t)(n0 + tid) * XSTRIDE;
        cc[tid][0] = 2.0f * xr[0];
        cc[tid][1] = xr[1];
        cc[tid][2] = xr[2];
    }
    __syncthreads();

    UPDATE_PHASE_A(Fp, Sp, Wa_, ba_)

    // ---- Phase B: z = F2 @ W1 + b1 (A from LDS, no role scale) ----
    frag_cd az[4][2];
    #pragma unroll
    for (int nt = 0; nt < 4; ++nt)
        #pragma unroll
        for (int ct = 0; ct < 2; ++ct)
            az[nt][ct] = (frag_cd){0.f, 0.f, 0.f, 0.f};

    frag_h bZ[4][2];
    #pragma unroll
    for (int c = 0; c < 4; ++c)
        #pragma unroll
        for (int ct = 0; ct < 2; ++ct)
            bZ[c][ct] = *(const frag_h*)(
                W1T + (size_t)(w32 + ct * 16 + lb) * 128 + c * 32 + q * 8);

    #pragma unroll
    for (int c = 0; c < 4; ++c) {
        frag_h aZ[4];
        #pragma unroll
        for (int nt = 0; nt < 4; ++nt)
            aZ[nt] = *(const frag_h*)&Fs[nt * 16 + lb][c * 32 + q * 8];
        #pragma unroll
        for (int ct = 0; ct < 2; ++ct)
            #pragma unroll
            for (int nt = 0; nt < 4; ++nt)
                az[nt][ct] = __builtin_amdgcn_mfma_f32_16x16x32_f16(
                    aZ[nt], bZ[c][ct], az[nt][ct], 0, 0, 0);
    }
    #pragma unroll
    for (int ct = 0; ct < 2; ++ct) {
        int col = w32 + ct * 16 + lb;
        float bb = b1[col];
        #pragma unroll
        for (int nt = 0; nt < 4; ++nt)
            #pragma unroll
            for (int rg = 0; rg < 4; ++rg)
                Z[nt * 16 + q * 4 + rg][col] = (_Float16)(az[nt][ct][rg] + bb);
    }
    __syncthreads();

    // ---- Phase C: logits = z@W2 + b2 (wave = 16-row tile), log_softmax ----
    frag_cd a2[3];
    #pragma unroll
    for (int ct = 0; ct < 3; ++ct) a2[ct] = (frag_cd){0.f, 0.f, 0.f, 0.f};
    #pragma unroll
    for (int ch = 0; ch < 4; ++ch) {
        frag_h zF = *(const frag_h*)&Z[wv * 16 + lb][ch * 32 + q * 8];
        #pragma unroll
        for (int ct = 0; ct < 3; ++ct) {
            frag_h bF = *(const frag_h*)(W2T + (size_t)(ct * 16 + lb) * 128 + ch * 32 + q * 8);
            a2[ct] = __builtin_amdgcn_mfma_f32_16x16x32_f16(zF, bF, a2[ct], 0, 0, 0);
        }
    }

    float lg[3][4];
    #pragma unroll
    for (int ct = 0; ct < 3; ++ct) {
        int col = ct * 16 + lb;
        bool valid = col < 40;
        float bb = valid ? b2[col] : -1e30f;
        #pragma unroll
        for (int rg = 0; rg < 4; ++rg)
            lg[ct][rg] = valid ? (a2[ct][rg] + bb) : -1e30f;
    }
    #pragma unroll
    for (int rg = 0; rg < 4; ++rg) {
        float mx = fmaxf(fmaxf(lg[0][rg], lg[1][rg]), lg[2][rg]);
        #pragma unroll
        for (int m = 1; m < 16; m <<= 1) mx = fmaxf(mx, __shfl_xor(mx, m, 64));
        float sm = __expf(lg[0][rg] - mx) + __expf(lg[1][rg] - mx) + __expf(lg[2][rg] - mx);
        #pragma unroll
        for (int m = 1; m < 16; m <<= 1) sm += __shfl_xor(sm, m, 64);
        float ls = mx + __logf(sm);
        int row = n0 + wv * 16 + q * 4 + rg;
        #pragma unroll
        for (int ct = 0; ct < 3; ++ct) {
            int col = ct * 16 + lb;
            if (col < 40) out[(size_t)row * 40 + col] = lg[ct][rg] - ls;
        }
    }
}

extern "C" void kernel_launch(void* const* d_in, const int* in_sizes, int n_in,
                              void* d_out, int out_size, void* d_ws, size_t ws_size,
                              hipStream_t stream) {
    const float* x  = (const float*)d_in[0];
    const int*   ei = (const int*)d_in[1];
    const float* Wm = (const float*)d_in[2];
    const float* bm = (const float*)d_in[3];
    const float* Wa = (const float*)d_in[4];
    const float* ba = (const float*)d_in[5];
    const float* W1 = (const float*)d_in[6];
    const float* b1 = (const float*)d_in[7];
    const float* W2 = (const float*)d_in[8];
    const float* b2 = (const float*)d_in[9];
    float* out = (float*)d_out;

    const int N = in_sizes[0] / XSTRIDE;   // 40000
    const int E = in_sizes[1] / 2;         // 480000
    const int NB = (N + 255) / 256;        // 157
    const size_t P = (size_t)N * 128;      // plane elements

    // workspace carve (16B-aligned)
    _Float16* Mb  = (_Float16*)d_ws;       // msg fp16
    _Float16* X   = Mb + P;                // x feats fp16
    _Float16* S   = X + P;                 // aggr fp16
    _Float16* F1  = S + P;                 // layer-1 out fp16
    _Float16* WmT = F1 + P;
    _Float16* WaT = WmT + CW_M;
    _Float16* W1T = WaT + CW_A;
    _Float16* W2T = W1T + CW_1;
    int* cnt   = (int*)(W2T + CW_2);       // N (memset together with fc)
    int* fc    = cnt + N;                  // N
    int* offs  = fc + N;                   // N+1
    int* csr   = offs + N + 1;             // E
    int* bsums = csr + E;                  // NB

    // ---- prep: zero counters, then merged convert+count ----
    hipMemsetAsync(cnt, 0, (size_t)2 * N * sizeof(int), stream);
    const int prep_total = CW_TOT + N * 16 + E;
    prep_kernel<<<(prep_total + 255) / 256, 256, 0, stream>>>(
        Wm, Wa, W1, W2, WmT, WaT, W1T, W2T, x, X, ei, cnt, N, E);

    // ---- CSR: scanA -> scanC(inline scanB) -> fill ----
    scanA<<<NB, 256, 0, stream>>>(cnt, N, bsums);
    scanC<<<NB, 256, 0, stream>>>(cnt, N, NB, bsums, offs);
    fill_kernel<<<(E + 255) / 256, 256, 0, stream>>>(ei, E, offs, fc, csr);

    const int gblk = N / 64;               // 625
    const int ablk = (N + 15) / 16;        // 2500

    // layer 1 msg
    msg_kernel<<<gblk, 256, 0, stream>>>(x, X, WmT, bm, Mb);
    agg_kernel<<<ablk, 256, 0, stream>>>(csr, offs, Mb, S, N);
    // layer-1 update + layer-2 msg (fused)
    fused_upd_msg<<<gblk, 256, 0, stream>>>(
        x, X, S, WaT, ba,
        WmT + (size_t)3 * 128 * 128, bm + (size_t)4 * 128, F1, Mb);
    agg_kernel<<<ablk, 256, 0, stream>>>(csr, offs, Mb, S, N);
    // layer-2 update + final MLP + log_softmax (fused)
    fused_upd_final<<<gblk, 256, 0, stream>>>(
        x, F1, S, WaT + (size_t)3 * 128 * 256, ba + (size_t)4 * 128,
        W1T, b1, W2T, b2, out);
}

// Round 12
// 270.357 us; speedup vs baseline: 1.3679x; 1.0394x over previous
//
#include <hip/hip_runtime.h>
#include <hip/hip_fp16.h>

#define RN 4
#define XSTRIDE 132   // R + DIN

typedef float    frag_cd __attribute__((ext_vector_type(4)));
typedef _Float16 frag_h  __attribute__((ext_vector_type(8)));

#define CW_M  (6 * 128 * 128)
#define CW_A  (6 * 128 * 256)
#define CW_1  (128 * 128)
#define CW_2  (48 * 128)
#define CW_TOT (CW_M + CW_A + CW_1 + CW_2)

// ---------------- merged prep: weight converts + x convert + degree count ---
__global__ void prep_kernel(
    const float* __restrict__ Wm, const float* __restrict__ Wa,
    const float* __restrict__ W1, const float* __restrict__ W2,
    _Float16* __restrict__ WmT, _Float16* __restrict__ WaT,
    _Float16* __restrict__ W1T, _Float16* __restrict__ W2T,
    const float* __restrict__ x, _Float16* __restrict__ X,
    const int* __restrict__ ei, int* __restrict__ cnt, int N, int E)
{
    int id = blockIdx.x * 256 + threadIdx.x;
    if (id < CW_M) {
        const int K = 128;
        int per = K * 128;
        int lr = id / per;  int l = lr / 3, r = lr - l * 3;
        int rem = id - lr * per;
        int k = rem >> 7, col = rem & 127;
        WmT[((size_t)lr * 128 + col) * K + k] =
            (_Float16)Wm[(((size_t)l * 4 + r) * K + k) * 128 + col];
        return;
    }
    id -= CW_M;
    if (id < CW_A) {
        const int K = 256;
        int per = K * 128;
        int lr = id / per;  int l = lr / 3, r = lr - l * 3;
        int rem = id - lr * per;
        int k = rem >> 7, col = rem & 127;
        WaT[((size_t)lr * 128 + col) * K + k] =
            (_Float16)Wa[(((size_t)l * 4 + r) * K + k) * 128 + col];
        return;
    }
    id -= CW_A;
    if (id < CW_1) {
        int col = id >> 7, k = id & 127;
        W1T[id] = (_Float16)W1[k * 128 + col];
        return;
    }
    id -= CW_1;
    if (id < CW_2) {
        int col = id >> 7, k = id & 127;
        W2T[id] = (_Float16)((col < 40) ? W2[k * 40 + col] : 0.0f);
        return;
    }
    id -= CW_2;
    if (id < N * 16) {              // x convert: 8 floats -> 8 halves
        int n = id >> 4, g = id & 15;
        const float4* src = (const float4*)(x + (size_t)n * XSTRIDE + RN + g * 8);
        float4 f0 = src[0], f1 = src[1];
        __half2 h0 = __float22half2_rn(make_float2(f0.x, f0.y));
        __half2 h1 = __float22half2_rn(make_float2(f0.z, f0.w));
        __half2 h2 = __float22half2_rn(make_float2(f1.x, f1.y));
        __half2 h3 = __float22half2_rn(make_float2(f1.z, f1.w));
        uint4 st; st.x = *(uint*)&h0; st.y = *(uint*)&h1;
        st.z = *(uint*)&h2; st.w = *(uint*)&h3;
        ((uint4*)X)[(size_t)n * 16 + g] = st;
        return;
    }
    id -= N * 16;
    if (id < E) atomicAdd(&cnt[ei[E + id]], 1);
}

// ---------------- CSR scans ------------------------------------------------
__global__ void scanA(const int* __restrict__ cnt, int N, int* __restrict__ bsums) {
    __shared__ int s[256];
    int t = threadIdx.x, n = blockIdx.x * 256 + t;
    s[t] = (n < N) ? cnt[n] : 0;
    __syncthreads();
    for (int off = 128; off > 0; off >>= 1) {
        if (t < off) s[t] += s[t + off];
        __syncthreads();
    }
    if (t == 0) bsums[blockIdx.x] = s[0];
}

__global__ void scanC(const int* __restrict__ cnt, int N, int nb,
                      const int* __restrict__ bsums, int* __restrict__ offs) {
    __shared__ int s[256];
    __shared__ int basebuf[256];
    int t = threadIdx.x, n = blockIdx.x * 256 + t;
    int bid = blockIdx.x;
    basebuf[t] = (t < bid && t < nb) ? bsums[t] : 0;
    __syncthreads();
    for (int off = 128; off > 0; off >>= 1) {
        if (t < off) basebuf[t] += basebuf[t + off];
        __syncthreads();
    }
    int base = basebuf[0];
    int v = (n < N) ? cnt[n] : 0;
    s[t] = v; __syncthreads();
    for (int off = 1; off < 256; off <<= 1) {
        int add = (t >= off) ? s[t - off] : 0;
        __syncthreads();
        s[t] += add;
        __syncthreads();
    }
    if (n < N) {
        offs[n] = base + s[t] - v;
        if (n == N - 1) offs[N] = base + s[t];
    }
}

__global__ void fill_kernel(const int* __restrict__ ei, int E,
                            const int* __restrict__ offs, int* __restrict__ fc,
                            int* __restrict__ csr) {
    int e = blockIdx.x * 256 + threadIdx.x;
    if (e < E) {
        int dst = ei[E + e];
        int p = offs[dst] + atomicAdd(&fc[dst], 1);
        csr[p] = ei[e];
    }
}

// ---------------- aggregate: mean over in-edges of Mb (fp16) ---------------
__global__ __launch_bounds__(256) void agg_kernel(
    const int* __restrict__ csr, const int* __restrict__ offs,
    const _Float16* __restrict__ Mb, _Float16* __restrict__ S, int N)
{
    int node = blockIdx.x * 16 + (threadIdx.x >> 4);
    int lane = threadIdx.x & 15;
    if (node >= N) return;
    int lo = offs[node], hi = offs[node + 1];
    const uint4* M4 = (const uint4*)Mb;     // row = 16 x uint4
    float a[8];
    #pragma unroll
    for (int i = 0; i < 8; ++i) a[i] = 0.0f;
    int e = lo;
    for (; e + 3 < hi; e += 4) {
        #pragma unroll
        for (int j = 0; j < 4; ++j) {
            uint4 u = M4[(size_t)csr[e + j] * 16 + lane];
            float2 f0 = __half22float2(*(const __half2*)&u.x);
            float2 f1 = __half22float2(*(const __half2*)&u.y);
            float2 f2 = __half22float2(*(const __half2*)&u.z);
            float2 f3 = __half22float2(*(const __half2*)&u.w);
            a[0] += f0.x; a[1] += f0.y; a[2] += f1.x; a[3] += f1.y;
            a[4] += f2.x; a[5] += f2.y; a[6] += f3.x; a[7] += f3.y;
        }
    }
    for (; e < hi; ++e) {
        uint4 u = M4[(size_t)csr[e] * 16 + lane];
        float2 f0 = __half22float2(*(const __half2*)&u.x);
        float2 f1 = __half22float2(*(const __half2*)&u.y);
        float2 f2 = __half22float2(*(const __half2*)&u.z);
        float2 f3 = __half22float2(*(const __half2*)&u.w);
        a[0] += f0.x; a[1] += f0.y; a[2] += f1.x; a[3] += f1.y;
        a[4] += f2.x; a[5] += f2.y; a[6] += f3.x; a[7] += f3.y;
    }
    float inv = (hi > lo) ? 1.0f / (float)(hi - lo) : 0.0f;
    __half2 h0 = __float22half2_rn(make_float2(a[0] * inv, a[1] * inv));
    __half2 h1 = __float22half2_rn(make_float2(a[2] * inv, a[3] * inv));
    __half2 h2 = __float22half2_rn(make_float2(a[4] * inv, a[5] * inv));
    __half2 h3 = __float22half2_rn(make_float2(a[6] * inv, a[7] * inv));
    uint4 st; st.x = *(uint*)&h0; st.y = *(uint*)&h1;
    st.z = *(uint*)&h2; st.w = *(uint*)&h3;
    ((uint4*)S)[(size_t)node * 16 + lane] = st;
}

// ---- helper: stage one [64][128] fp16 global plane tile into padded LDS ----
#define STAGE_TILE(dst, src, n0, tid)                                         \
    _Pragma("unroll")                                                         \
    for (int i_ = 0; i_ < 4; ++i_) {                                          \
        int idx_ = i_ * 256 + (tid);                                          \
        int row_ = idx_ >> 4, g_ = idx_ & 15;                                 \
        *(uint4*)&(dst)[row_][g_ * 8] =                                       \
            ((const uint4*)(src))[((size_t)((n0) + row_)) * 16 + g_];         \
    }

// ---------------- layer-1 msg GEMM (A from LDS, full B prefetch) -----------
// Mb = relu(sum_r c_r (X @ Wm_r + bm_r)); single acc via role-scaled A.
__global__ __launch_bounds__(256) void msg_kernel(
    const float* __restrict__ x,
    const _Float16* __restrict__ Fp,               // [N][128]
    const _Float16* __restrict__ W,                // [3][128][128]
    const float* __restrict__ bias,                // [4][128]
    _Float16* __restrict__ out)
{
    __shared__ _Float16 As[64][136];
    __shared__ float cc[64][3];

    const int tid = threadIdx.x;
    const int n0 = blockIdx.x * 64;
    const int lane = tid & 63;
    const int wv = tid >> 6;
    const int q = lane >> 4;
    const int lb = lane & 15;
    const int w32 = wv * 32;

    if (tid < 64) {
        const float* xr = x + (size_t)(n0 + tid) * XSTRIDE;
        cc[tid][0] = 2.0f * xr[0];
        cc[tid][1] = xr[1];
        cc[tid][2] = xr[2];
    }
    STAGE_TILE(As, Fp, n0, tid)
    __syncthreads();

    _Float16 ch16[4][3];
    #pragma unroll
    for (int nt = 0; nt < 4; ++nt)
        #pragma unroll
        for (int r = 0; r < 3; ++r)
            ch16[nt][r] = (_Float16)cc[nt * 16 + lb][r];

    frag_cd acc[4][2];
    #pragma unroll
    for (int nt = 0; nt < 4; ++nt)
        #pragma unroll
        for (int ct = 0; ct < 2; ++ct)
            acc[nt][ct] = (frag_cd){0.f, 0.f, 0.f, 0.f};

    // full B prefetch (24 frags)
    frag_h bF[4][6];
    #pragma unroll
    for (int c = 0; c < 4; ++c)
        #pragma unroll
        for (int r = 0; r < 3; ++r)
            #pragma unroll
            for (int ct = 0; ct < 2; ++ct)
                bF[c][r * 2 + ct] = *(const frag_h*)(
                    W + ((size_t)(r * 128 + w32 + ct * 16 + lb)) * 128 + c * 32 + q * 8);

    // A double-buffer from LDS
    frag_h aL[2][4];
    #pragma unroll
    for (int nt = 0; nt < 4; ++nt)
        aL[0][nt] = *(const frag_h*)&As[nt * 16 + lb][q * 8];

    #pragma unroll
    for (int c = 0; c < 4; ++c) {
        if (c + 1 < 4) {
            #pragma unroll
            for (int nt = 0; nt < 4; ++nt)
                aL[(c + 1) & 1][nt] = *(const frag_h*)&As[nt * 16 + lb][(c + 1) * 32 + q * 8];
        }
        #pragma unroll
        for (int r = 0; r < 3; ++r)
            #pragma unroll
            for (int nt = 0; nt < 4; ++nt) {
                frag_h sa = aL[c & 1][nt] * ch16[nt][r];
                #pragma unroll
                for (int ct = 0; ct < 2; ++ct)
                    acc[nt][ct] = __builtin_amdgcn_mfma_f32_16x16x32_f16(
                        sa, bF[c][r * 2 + ct], acc[nt][ct], 0, 0, 0);
            }
    }

    #pragma unroll
    for (int ct = 0; ct < 2; ++ct) {
        int col = w32 + ct * 16 + lb;
        float b0 = bias[col], b1 = bias[128 + col], b2 = bias[256 + col];
        #pragma unroll
        for (int nt = 0; nt < 4; ++nt)
            #pragma unroll
            for (int rg = 0; rg < 4; ++rg) {
                int row = nt * 16 + q * 4 + rg;
                float v = acc[nt][ct][rg]
                        + cc[row][0] * b0 + cc[row][1] * b1 + cc[row][2] * b2;
                out[(size_t)(n0 + row) * 128 + col] = (_Float16)fmaxf(v, 0.0f);
            }
    }
}

// ====== PHASE-A MACRO: update GEMM (KV=256), A from LDS As/Ss, B global =====
// Requires in scope: As, Ss, Fs, cc, red, tid, n0, lane, wv, q, lb, w32.
// Result: normalized relu'd rows in Fs; ch16/acc-era regs left defined.
#define UPDATE_PHASE_A_LDS(Wa_, ba_)                                          \
    _Float16 ch16[4][3];                                                      \
    _Pragma("unroll")                                                         \
    for (int nt = 0; nt < 4; ++nt)                                            \
        _Pragma("unroll")                                                     \
        for (int r = 0; r < 3; ++r)                                           \
            ch16[nt][r] = (_Float16)cc[nt * 16 + lb][r];                      \
    frag_cd acc[4][2];                                                        \
    _Pragma("unroll")                                                         \
    for (int nt = 0; nt < 4; ++nt)                                            \
        _Pragma("unroll")                                                     \
        for (int ct = 0; ct < 2; ++ct)                                        \
            acc[nt][ct] = (frag_cd){0.f, 0.f, 0.f, 0.f};                      \
    size_t wrow[3][2];                                                        \
    _Pragma("unroll")                                                         \
    for (int r = 0; r < 3; ++r)                                               \
        _Pragma("unroll")                                                     \
        for (int ct = 0; ct < 2; ++ct)                                        \
            wrow[r][ct] = ((size_t)(r * 128 + w32 + ct * 16 + lb)) * 256 + q * 8; \
    {                                                                         \
        frag_h bF[3][6];                                                      \
        auto loadB = [&](int c, int buf) {                                    \
            _Pragma("unroll")                                                 \
            for (int r = 0; r < 3; ++r)                                       \
                _Pragma("unroll")                                             \
                for (int ct = 0; ct < 2; ++ct)                                \
                    bF[buf][r * 2 + ct] = *(const frag_h*)((Wa_) + wrow[r][ct] + c * 32); \
        };                                                                    \
        loadB(0, 0);                                                          \
        loadB(1, 1);                                                          \
        frag_h aL[2][4];                                                      \
        _Pragma("unroll")                                                     \
        for (int nt = 0; nt < 4; ++nt)                                        \
            aL[0][nt] = *(const frag_h*)&As[nt * 16 + lb][q * 8];             \
        _Pragma("unroll")                                                     \
        for (int ch = 0; ch < 8; ++ch) {                                      \
            if (ch + 2 < 8) loadB(ch + 2, (ch + 2) % 3);                      \
            if (ch + 1 < 8) {                                                 \
                const int c1 = ch + 1;                                        \
                _Pragma("unroll")                                             \
                for (int nt = 0; nt < 4; ++nt)                                \
                    aL[c1 & 1][nt] = (c1 < 4)                                 \
                        ? *(const frag_h*)&As[nt * 16 + lb][c1 * 32 + q * 8]  \
                        : *(const frag_h*)&Ss[nt * 16 + lb][(c1 - 4) * 32 + q * 8]; \
            }                                                                 \
            const int cur = ch % 3;                                           \
            _Pragma("unroll")                                                 \
            for (int r = 0; r < 3; ++r)                                       \
                _Pragma("unroll")                                             \
                for (int nt = 0; nt < 4; ++nt) {                              \
                    frag_h sa = aL[ch & 1][nt] * ch16[nt][r];                 \
                    _Pragma("unroll")                                         \
                    for (int ct = 0; ct < 2; ++ct)                            \
                        acc[nt][ct] = __builtin_amdgcn_mfma_f32_16x16x32_f16( \
                            sa, bF[cur][r * 2 + ct], acc[nt][ct], 0, 0, 0);   \
                }                                                             \
        }                                                                     \
    }                                                                         \
    float vv[4][2][4];                                                        \
    _Pragma("unroll")                                                         \
    for (int ct = 0; ct < 2; ++ct) {                                          \
        int col = w32 + ct * 16 + lb;                                         \
        float b0 = (ba_)[col], b1 = (ba_)[128 + col], b2 = (ba_)[256 + col];  \
        _Pragma("unroll")                                                     \
        for (int nt = 0; nt < 4; ++nt)                                        \
            _Pragma("unroll")                                                 \
            for (int rg = 0; rg < 4; ++rg) {                                  \
                int row = nt * 16 + q * 4 + rg;                               \
                float v = acc[nt][ct][rg]                                     \
                        + cc[row][0] * b0 + cc[row][1] * b1 + cc[row][2] * b2;\
                vv[nt][ct][rg] = fmaxf(v, 0.0f);                              \
            }                                                                 \
    }                                                                         \
    _Pragma("unroll")                                                         \
    for (int nt = 0; nt < 4; ++nt)                                            \
        _Pragma("unroll")                                                     \
        for (int rg = 0; rg < 4; ++rg) {                                      \
            float ss = vv[nt][0][rg] * vv[nt][0][rg] + vv[nt][1][rg] * vv[nt][1][rg]; \
            _Pragma("unroll")                                                 \
            for (int m = 1; m < 16; m <<= 1) ss += __shfl_xor(ss, m, 64);     \
            if (lb == 0) red[nt * 16 + q * 4 + rg][wv] = ss;                  \
        }                                                                     \
    __syncthreads();                                                          \
    _Pragma("unroll")                                                         \
    for (int nt = 0; nt < 4; ++nt)                                            \
        _Pragma("unroll")                                                     \
        for (int rg = 0; rg < 4; ++rg) {                                      \
            int row = nt * 16 + q * 4 + rg;                                   \
            float t = red[row][0] + red[row][1] + red[row][2] + red[row][3];  \
            float inv = 1.0f / fmaxf(sqrtf(t), 1e-12f);                       \
            _Pragma("unroll")                                                 \
            for (int ct = 0; ct < 2; ++ct)                                    \
                Fs[row][w32 + ct * 16 + lb] = (_Float16)(vv[nt][ct][rg] * inv); \
        }                                                                     \
    __syncthreads();

// ---------------- fused: layer update (norm) + next-layer msg --------------
__global__ __launch_bounds__(256) void fused_upd_msg(
    const float* __restrict__ x,
    const _Float16* __restrict__ Fp, const _Float16* __restrict__ Sp,
    const _Float16* __restrict__ Wa_, const float* __restrict__ ba_,
    const _Float16* __restrict__ Wm2, const float* __restrict__ bm2,
    _Float16* __restrict__ F1, _Float16* __restrict__ Mb)
{
    __shared__ _Float16 As[64][136];
    __shared__ _Float16 Ss[64][136];
    __shared__ _Float16 Fs[64][136];
    __shared__ float cc[64][3];
    __shared__ float red[64][4];

    const int tid = threadIdx.x;
    const int n0 = blockIdx.x * 64;
    const int lane = tid & 63;
    const int wv = tid >> 6;
    const int q = lane >> 4;
    const int lb = lane & 15;
    const int w32 = wv * 32;

    if (tid < 64) {
        const float* xr = x + (size_t)(n0 + tid) * XSTRIDE;
        cc[tid][0] = 2.0f * xr[0];
        cc[tid][1] = xr[1];
        cc[tid][2] = xr[2];
    }
    STAGE_TILE(As, Fp, n0, tid)
    STAGE_TILE(Ss, Sp, n0, tid)
    __syncthreads();

    UPDATE_PHASE_A_LDS(Wa_, ba_)

    // write F1 global, coalesced 16-B stores from LDS
    #pragma unroll
    for (int i = 0; i < 4; ++i) {
        int idx = i * 256 + tid;             // 0..1023
        int row = idx >> 4, g = idx & 15;
        ((uint4*)F1)[(size_t)(n0 + row) * 16 + g] = *(const uint4*)&Fs[row][g * 8];
    }

    // ---- Phase B: msg GEMM, A from LDS Fs ----
    frag_cd a2[4][2];
    #pragma unroll
    for (int nt = 0; nt < 4; ++nt)
        #pragma unroll
        for (int ct = 0; ct < 2; ++ct)
            a2[nt][ct] = (frag_cd){0.f, 0.f, 0.f, 0.f};

    frag_h bB[4][6];
    #pragma unroll
    for (int c = 0; c < 4; ++c)
        #pragma unroll
        for (int r = 0; r < 3; ++r)
            #pragma unroll
            for (int ct = 0; ct < 2; ++ct)
                bB[c][r * 2 + ct] = *(const frag_h*)(
                    Wm2 + ((size_t)(r * 128 + w32 + ct * 16 + lb)) * 128 + c * 32 + q * 8);

    #pragma unroll
    for (int c = 0; c < 4; ++c) {
        frag_h aM[4];
        #pragma unroll
        for (int nt = 0; nt < 4; ++nt)
            aM[nt] = *(const frag_h*)&Fs[nt * 16 + lb][c * 32 + q * 8];
        #pragma unroll
        for (int r = 0; r < 3; ++r)
            #pragma unroll
            for (int nt = 0; nt < 4; ++nt) {
                frag_h sa = aM[nt] * ch16[nt][r];
                #pragma unroll
                for (int ct = 0; ct < 2; ++ct)
                    a2[nt][ct] = __builtin_amdgcn_mfma_f32_16x16x32_f16(
                        sa, bB[c][r * 2 + ct], a2[nt][ct], 0, 0, 0);
            }
    }

    #pragma unroll
    for (int ct = 0; ct < 2; ++ct) {
        int col = w32 + ct * 16 + lb;
        float b0 = bm2[col], b1 = bm2[128 + col], b2 = bm2[256 + col];
        #pragma unroll
        for (int nt = 0; nt < 4; ++nt)
            #pragma unroll
            for (int rg = 0; rg < 4; ++rg) {
                int row = nt * 16 + q * 4 + rg;
                float v = a2[nt][ct][rg]
                        + cc[row][0] * b0 + cc[row][1] * b1 + cc[row][2] * b2;
                Mb[(size_t)(n0 + row) * 128 + col] = (_Float16)fmaxf(v, 0.0f);
            }
    }
}

// ---------------- fused: layer-2 update + final MLP + log_softmax ----------
// Z aliases the As staging region (A reads complete before Fs barrier).
__global__ __launch_bounds__(256) void fused_upd_final(
    const float* __restrict__ x,
    const _Float16* __restrict__ Fp, const _Float16* __restrict__ Sp,
    const _Float16* __restrict__ Wa_, const float* __restrict__ ba_,
    const _Float16* __restrict__ W1T, const float* __restrict__ b1,
    const _Float16* __restrict__ W2T, const float* __restrict__ b2,
    float* __restrict__ out)
{
    __shared__ _Float16 As[64][136];   // phase A: Fp stage; phase B/C: Z
    __shared__ _Float16 Ss[64][136];
    __shared__ _Float16 Fs[64][136];
    __shared__ float cc[64][3];
    __shared__ float red[64][4];

    const int tid = threadIdx.x;
    const int n0 = blockIdx.x * 64;
    const int lane = tid & 63;
    const int wv = tid >> 6;
    const int q = lane >> 4;
    const int lb = lane & 15;
    const int w32 = wv * 32;

    if (tid < 64) {
        const float* xr = x + (size_t)(n0 + tid) * XSTRIDE;
        cc[tid][0] = 2.0f * xr[0];
        cc[tid][1] = xr[1];
        cc[tid][2] = xr[2];
    }
    STAGE_TILE(As, Fp, n0, tid)
    STAGE_TILE(Ss, Sp, n0, tid)
    __syncthreads();

    UPDATE_PHASE_A_LDS(Wa_, ba_)

    // ---- Phase B: z = F2 @ W1 + b1 (A from LDS Fs) ----
    frag_cd az[4][2];
    #pragma unroll
    for (int nt = 0; nt < 4; ++nt)
        #pragma unroll
        for (int ct = 0; ct < 2; ++ct)
            az[nt][ct] = (frag_cd){0.f, 0.f, 0.f, 0.f};

    frag_h bZ[4][2];
    #pragma unroll
    for (int c = 0; c < 4; ++c)
        #pragma unroll
        for (int ct = 0; ct < 2; ++ct)
            bZ[c][ct] = *(const frag_h*)(
                W1T + (size_t)(w32 + ct * 16 + lb) * 128 + c * 32 + q * 8);

    #pragma unroll
    for (int c = 0; c < 4; ++c) {
        frag_h aZ[4];
        #pragma unroll
        for (int nt = 0; nt < 4; ++nt)
            aZ[nt] = *(const frag_h*)&Fs[nt * 16 + lb][c * 32 + q * 8];
        #pragma unroll
        for (int ct = 0; ct < 2; ++ct)
            #pragma unroll
            for (int nt = 0; nt < 4; ++nt)
                az[nt][ct] = __builtin_amdgcn_mfma_f32_16x16x32_f16(
                    aZ[nt], bZ[c][ct], az[nt][ct], 0, 0, 0);
    }
    #pragma unroll
    for (int ct = 0; ct < 2; ++ct) {
        int col = w32 + ct * 16 + lb;
        float bb = b1[col];
        #pragma unroll
        for (int nt = 0; nt < 4; ++nt)
            #pragma unroll
            for (int rg = 0; rg < 4; ++rg)
                As[nt * 16 + q * 4 + rg][col] = (_Float16)(az[nt][ct][rg] + bb);  // Z
    }
    __syncthreads();

    // ---- Phase C: logits = z@W2 + b2 (wave = 16-row tile), log_softmax ----
    frag_cd a2[3];
    #pragma unroll
    for (int ct = 0; ct < 3; ++ct) a2[ct] = (frag_cd){0.f, 0.f, 0.f, 0.f};
    #pragma unroll
    for (int ch = 0; ch < 4; ++ch) {
        frag_h zF = *(const frag_h*)&As[wv * 16 + lb][ch * 32 + q * 8];
        #pragma unroll
        for (int ct = 0; ct < 3; ++ct) {
            frag_h bF = *(const frag_h*)(W2T + (size_t)(ct * 16 + lb) * 128 + ch * 32 + q * 8);
            a2[ct] = __builtin_amdgcn_mfma_f32_16x16x32_f16(zF, bF, a2[ct], 0, 0, 0);
        }
    }

    float lg[3][4];
    #pragma unroll
    for (int ct = 0; ct < 3; ++ct) {
        int col = ct * 16 + lb;
        bool valid = col < 40;
        float bb = valid ? b2[col] : -1e30f;
        #pragma unroll
        for (int rg = 0; rg < 4; ++rg)
            lg[ct][rg] = valid ? (a2[ct][rg] + bb) : -1e30f;
    }
    #pragma unroll
    for (int rg = 0; rg < 4; ++rg) {
        float mx = fmaxf(fmaxf(lg[0][rg], lg[1][rg]), lg[2][rg]);
        #pragma unroll
        for (int m = 1; m < 16; m <<= 1) mx = fmaxf(mx, __shfl_xor(mx, m, 64));
        float sm = __expf(lg[0][rg] - mx) + __expf(lg[1][rg] - mx) + __expf(lg[2][rg] - mx);
        #pragma unroll
        for (int m = 1; m < 16; m <<= 1) sm += __shfl_xor(sm, m, 64);
        float ls = mx + __logf(sm);
        int row = n0 + wv * 16 + q * 4 + rg;
        #pragma unroll
        for (int ct = 0; ct < 3; ++ct) {
            int col = ct * 16 + lb;
            if (col < 40) out[(size_t)row * 40 + col] = lg[ct][rg] - ls;
        }
    }
}

extern "C" void kernel_launch(void* const* d_in, const int* in_sizes, int n_in,
                              void* d_out, int out_size, void* d_ws, size_t ws_size,
                              hipStream_t stream) {
    const float* x  = (const float*)d_in[0];
    const int*   ei = (const int*)d_in[1];
    const float* Wm = (const float*)d_in[2];
    const float* bm = (const float*)d_in[3];
    const float* Wa = (const float*)d_in[4];
    const float* ba = (const float*)d_in[5];
    const float* W1 = (const float*)d_in[6];
    const float* b1 = (const float*)d_in[7];
    const float* W2 = (const float*)d_in[8];
    const float* b2 = (const float*)d_in[9];
    float* out = (float*)d_out;

    const int N = in_sizes[0] / XSTRIDE;   // 40000
    const int E = in_sizes[1] / 2;         // 480000
    const int NB = (N + 255) / 256;        // 157
    const size_t P = (size_t)N * 128;      // plane elements

    // workspace carve (16B-aligned)
    _Float16* Mb  = (_Float16*)d_ws;       // msg fp16
    _Float16* X   = Mb + P;                // x feats fp16
    _Float16* S   = X + P;                 // aggr fp16
    _Float16* F1  = S + P;                 // layer-1 out fp16
    _Float16* WmT = F1 + P;
    _Float16* WaT = WmT + CW_M;
    _Float16* W1T = WaT + CW_A;
    _Float16* W2T = W1T + CW_1;
    int* cnt   = (int*)(W2T + CW_2);       // N (memset together with fc)
    int* fc    = cnt + N;                  // N
    int* offs  = fc + N;                   // N+1
    int* csr   = offs + N + 1;             // E
    int* bsums = csr + E;                  // NB

    // ---- prep: zero counters, then merged convert+count ----
    hipMemsetAsync(cnt, 0, (size_t)2 * N * sizeof(int), stream);
    const int prep_total = CW_TOT + N * 16 + E;
    prep_kernel<<<(prep_total + 255) / 256, 256, 0, stream>>>(
        Wm, Wa, W1, W2, WmT, WaT, W1T, W2T, x, X, ei, cnt, N, E);

    // ---- CSR: scanA -> scanC(inline scanB) -> fill ----
    scanA<<<NB, 256, 0, stream>>>(cnt, N, bsums);
    scanC<<<NB, 256, 0, stream>>>(cnt, N, NB, bsums, offs);
    fill_kernel<<<(E + 255) / 256, 256, 0, stream>>>(ei, E, offs, fc, csr);

    const int gblk = N / 64;               // 625
    const int ablk = (N + 15) / 16;        // 2500

    // layer 1 msg
    msg_kernel<<<gblk, 256, 0, stream>>>(x, X, WmT, bm, Mb);
    agg_kernel<<<ablk, 256, 0, stream>>>(csr, offs, Mb, S, N);
    // layer-1 update + layer-2 msg (fused)
    fused_upd_msg<<<gblk, 256, 0, stream>>>(
        x, X, S, WaT, ba,
        WmT + (size_t)3 * 128 * 128, bm + (size_t)4 * 128, F1, Mb);
    agg_kernel<<<ablk, 256, 0, stream>>>(csr, offs, Mb, S, N);
    // layer-2 update + final MLP + log_softmax (fused)
    fused_upd_final<<<gblk, 256, 0, stream>>>(
        x, F1, S, WaT + (size_t)3 * 128 * 256, ba + (size_t)4 * 128,
        W1T, b1, W2T, b2, out);
}

// Round 13
// 266.104 us; speedup vs baseline: 1.3897x; 1.0160x over previous
//
#include <hip/hip_runtime.h>
#include <hip/hip_fp16.h>

#define RN 4
#define XSTRIDE 132   // R + DIN

typedef float    frag_cd __attribute__((ext_vector_type(4)));
typedef _Float16 frag_h  __attribute__((ext_vector_type(8)));

#define CW_M  (6 * 128 * 128)
#define CW_A  (6 * 128 * 256)
#define CW_1  (128 * 128)
#define CW_2  (48 * 128)
#define CW_TOT (CW_M + CW_A + CW_1 + CW_2)

// ---------------- merged prep: weight converts + x convert + degree count ---
__global__ void prep_kernel(
    const float* __restrict__ Wm, const float* __restrict__ Wa,
    const float* __restrict__ W1, const float* __restrict__ W2,
    _Float16* __restrict__ WmT, _Float16* __restrict__ WaT,
    _Float16* __restrict__ W1T, _Float16* __restrict__ W2T,
    const float* __restrict__ x, _Float16* __restrict__ X,
    const int* __restrict__ ei, int* __restrict__ cnt, int N, int E)
{
    int id = blockIdx.x * 256 + threadIdx.x;
    if (id < CW_M) {
        const int K = 128;
        int per = K * 128;
        int lr = id / per;  int l = lr / 3, r = lr - l * 3;
        int rem = id - lr * per;
        int k = rem >> 7, col = rem & 127;
        WmT[((size_t)lr * 128 + col) * K + k] =
            (_Float16)Wm[(((size_t)l * 4 + r) * K + k) * 128 + col];
        return;
    }
    id -= CW_M;
    if (id < CW_A) {
        const int K = 256;
        int per = K * 128;
        int lr = id / per;  int l = lr / 3, r = lr - l * 3;
        int rem = id - lr * per;
        int k = rem >> 7, col = rem & 127;
        WaT[((size_t)lr * 128 + col) * K + k] =
            (_Float16)Wa[(((size_t)l * 4 + r) * K + k) * 128 + col];
        return;
    }
    id -= CW_A;
    if (id < CW_1) {
        int col = id >> 7, k = id & 127;
        W1T[id] = (_Float16)W1[k * 128 + col];
        return;
    }
    id -= CW_1;
    if (id < CW_2) {
        int col = id >> 7, k = id & 127;
        W2T[id] = (_Float16)((col < 40) ? W2[k * 40 + col] : 0.0f);
        return;
    }
    id -= CW_2;
    if (id < N * 16) {              // x convert: 8 floats -> 8 halves
        int n = id >> 4, g = id & 15;
        const float4* src = (const float4*)(x + (size_t)n * XSTRIDE + RN + g * 8);
        float4 f0 = src[0], f1 = src[1];
        __half2 h0 = __float22half2_rn(make_float2(f0.x, f0.y));
        __half2 h1 = __float22half2_rn(make_float2(f0.z, f0.w));
        __half2 h2 = __float22half2_rn(make_float2(f1.x, f1.y));
        __half2 h3 = __float22half2_rn(make_float2(f1.z, f1.w));
        uint4 st; st.x = *(uint*)&h0; st.y = *(uint*)&h1;
        st.z = *(uint*)&h2; st.w = *(uint*)&h3;
        ((uint4*)X)[(size_t)n * 16 + g] = st;
        return;
    }
    id -= N * 16;
    if (id < E) atomicAdd(&cnt[ei[E + id]], 1);
}

// ---------------- CSR scans ------------------------------------------------
__global__ void scanA(const int* __restrict__ cnt, int N, int* __restrict__ bsums) {
    __shared__ int s[256];
    int t = threadIdx.x, n = blockIdx.x * 256 + t;
    s[t] = (n < N) ? cnt[n] : 0;
    __syncthreads();
    for (int off = 128; off > 0; off >>= 1) {
        if (t < off) s[t] += s[t + off];
        __syncthreads();
    }
    if (t == 0) bsums[blockIdx.x] = s[0];
}

__global__ void scanC(const int* __restrict__ cnt, int N, int nb,
                      const int* __restrict__ bsums, int* __restrict__ offs) {
    __shared__ int s[256];
    __shared__ int basebuf[256];
    int t = threadIdx.x, n = blockIdx.x * 256 + t;
    int bid = blockIdx.x;
    basebuf[t] = (t < bid && t < nb) ? bsums[t] : 0;
    __syncthreads();
    for (int off = 128; off > 0; off >>= 1) {
        if (t < off) basebuf[t] += basebuf[t + off];
        __syncthreads();
    }
    int base = basebuf[0];
    int v = (n < N) ? cnt[n] : 0;
    s[t] = v; __syncthreads();
    for (int off = 1; off < 256; off <<= 1) {
        int add = (t >= off) ? s[t - off] : 0;
        __syncthreads();
        s[t] += add;
        __syncthreads();
    }
    if (n < N) {
        offs[n] = base + s[t] - v;
        if (n == N - 1) offs[N] = base + s[t];
    }
}

__global__ void fill_kernel(const int* __restrict__ ei, int E,
                            const int* __restrict__ offs, int* __restrict__ fc,
                            int* __restrict__ csr) {
    int e = blockIdx.x * 256 + threadIdx.x;
    if (e < E) {
        int dst = ei[E + e];
        int p = offs[dst] + atomicAdd(&fc[dst], 1);
        csr[p] = ei[e];
    }
}

// ---------------- aggregate: mean over in-edges of Mb (fp16) ---------------
__global__ __launch_bounds__(256) void agg_kernel(
    const int* __restrict__ csr, const int* __restrict__ offs,
    const _Float16* __restrict__ Mb, _Float16* __restrict__ S, int N)
{
    int node = blockIdx.x * 16 + (threadIdx.x >> 4);
    int lane = threadIdx.x & 15;
    if (node >= N) return;
    int lo = offs[node], hi = offs[node + 1];
    const uint4* M4 = (const uint4*)Mb;     // row = 16 x uint4
    float a[8];
    #pragma unroll
    for (int i = 0; i < 8; ++i) a[i] = 0.0f;
    int e = lo;
    for (; e + 3 < hi; e += 4) {
        #pragma unroll
        for (int j = 0; j < 4; ++j) {
            uint4 u = M4[(size_t)csr[e + j] * 16 + lane];
            float2 f0 = __half22float2(*(const __half2*)&u.x);
            float2 f1 = __half22float2(*(const __half2*)&u.y);
            float2 f2 = __half22float2(*(const __half2*)&u.z);
            float2 f3 = __half22float2(*(const __half2*)&u.w);
            a[0] += f0.x; a[1] += f0.y; a[2] += f1.x; a[3] += f1.y;
            a[4] += f2.x; a[5] += f2.y; a[6] += f3.x; a[7] += f3.y;
        }
    }
    for (; e < hi; ++e) {
        uint4 u = M4[(size_t)csr[e] * 16 + lane];
        float2 f0 = __half22float2(*(const __half2*)&u.x);
        float2 f1 = __half22float2(*(const __half2*)&u.y);
        float2 f2 = __half22float2(*(const __half2*)&u.z);
        float2 f3 = __half22float2(*(const __half2*)&u.w);
        a[0] += f0.x; a[1] += f0.y; a[2] += f1.x; a[3] += f1.y;
        a[4] += f2.x; a[5] += f2.y; a[6] += f3.x; a[7] += f3.y;
    }
    float inv = (hi > lo) ? 1.0f / (float)(hi - lo) : 0.0f;
    __half2 h0 = __float22half2_rn(make_float2(a[0] * inv, a[1] * inv));
    __half2 h1 = __float22half2_rn(make_float2(a[2] * inv, a[3] * inv));
    __half2 h2 = __float22half2_rn(make_float2(a[4] * inv, a[5] * inv));
    __half2 h3 = __float22half2_rn(make_float2(a[6] * inv, a[7] * inv));
    uint4 st; st.x = *(uint*)&h0; st.y = *(uint*)&h1;
    st.z = *(uint*)&h2; st.w = *(uint*)&h3;
    ((uint4*)S)[(size_t)node * 16 + lane] = st;
}

// ---- helper: stage one [64][128] fp16 global plane tile into padded LDS ----
#define STAGE_TILE(dst, src, n0, tid)                                         \
    _Pragma("unroll")                                                         \
    for (int i_ = 0; i_ < 4; ++i_) {                                          \
        int idx_ = i_ * 256 + (tid);                                          \
        int row_ = idx_ >> 4, g_ = idx_ & 15;                                 \
        *(uint4*)&(dst)[row_][g_ * 8] =                                       \
            ((const uint4*)(src))[((size_t)((n0) + row_)) * 16 + g_];         \
    }

// ---------------- layer-1 msg GEMM (A from LDS, full B prefetch) -----------
__global__ __launch_bounds__(256) void msg_kernel(
    const float* __restrict__ x,
    const _Float16* __restrict__ Fp,               // [N][128]
    const _Float16* __restrict__ W,                // [3][128][128]
    const float* __restrict__ bias,                // [4][128]
    _Float16* __restrict__ out)
{
    __shared__ _Float16 As[64][136];
    __shared__ float cc[64][3];

    const int tid = threadIdx.x;
    const int n0 = blockIdx.x * 64;
    const int lane = tid & 63;
    const int wv = tid >> 6;
    const int q = lane >> 4;
    const int lb = lane & 15;
    const int w32 = wv * 32;

    if (tid < 64) {
        const float* xr = x + (size_t)(n0 + tid) * XSTRIDE;
        cc[tid][0] = 2.0f * xr[0];
        cc[tid][1] = xr[1];
        cc[tid][2] = xr[2];
    }
    STAGE_TILE(As, Fp, n0, tid)
    __syncthreads();

    _Float16 ch16[4][3];
    #pragma unroll
    for (int nt = 0; nt < 4; ++nt)
        #pragma unroll
        for (int r = 0; r < 3; ++r)
            ch16[nt][r] = (_Float16)cc[nt * 16 + lb][r];

    frag_cd acc[4][2];
    #pragma unroll
    for (int nt = 0; nt < 4; ++nt)
        #pragma unroll
        for (int ct = 0; ct < 2; ++ct)
            acc[nt][ct] = (frag_cd){0.f, 0.f, 0.f, 0.f};

    frag_h bF[4][6];
    #pragma unroll
    for (int c = 0; c < 4; ++c)
        #pragma unroll
        for (int r = 0; r < 3; ++r)
            #pragma unroll
            for (int ct = 0; ct < 2; ++ct)
                bF[c][r * 2 + ct] = *(const frag_h*)(
                    W + ((size_t)(r * 128 + w32 + ct * 16 + lb)) * 128 + c * 32 + q * 8);

    frag_h aL[2][4];
    #pragma unroll
    for (int nt = 0; nt < 4; ++nt)
        aL[0][nt] = *(const frag_h*)&As[nt * 16 + lb][q * 8];

    #pragma unroll
    for (int c = 0; c < 4; ++c) {
        if (c + 1 < 4) {
            #pragma unroll
            for (int nt = 0; nt < 4; ++nt)
                aL[(c + 1) & 1][nt] = *(const frag_h*)&As[nt * 16 + lb][(c + 1) * 32 + q * 8];
        }
        #pragma unroll
        for (int r = 0; r < 3; ++r)
            #pragma unroll
            for (int nt = 0; nt < 4; ++nt) {
                frag_h sa = aL[c & 1][nt] * ch16[nt][r];
                #pragma unroll
                for (int ct = 0; ct < 2; ++ct)
                    acc[nt][ct] = __builtin_amdgcn_mfma_f32_16x16x32_f16(
                        sa, bF[c][r * 2 + ct], acc[nt][ct], 0, 0, 0);
            }
    }

    #pragma unroll
    for (int ct = 0; ct < 2; ++ct) {
        int col = w32 + ct * 16 + lb;
        float b0 = bias[col], b1 = bias[128 + col], b2 = bias[256 + col];
        #pragma unroll
        for (int nt = 0; nt < 4; ++nt)
            #pragma unroll
            for (int rg = 0; rg < 4; ++rg) {
                int row = nt * 16 + q * 4 + rg;
                float v = acc[nt][ct][rg]
                        + cc[row][0] * b0 + cc[row][1] * b1 + cc[row][2] * b2;
                out[(size_t)(n0 + row) * 128 + col] = (_Float16)fmaxf(v, 0.0f);
            }
    }
}

// ====== PHASE-A MACRO: update GEMM (KV=256), A from LDS As/Ss, B global =====
// As last read at chunk 3, Ss at chunk 7 — both before the red barrier, so
// Fs may ALIAS As (declared by caller). Result: normalized rows in Fs.
#define UPDATE_PHASE_A_LDS(Wa_, ba_)                                          \
    _Float16 ch16[4][3];                                                      \
    _Pragma("unroll")                                                         \
    for (int nt = 0; nt < 4; ++nt)                                            \
        _Pragma("unroll")                                                     \
        for (int r = 0; r < 3; ++r)                                           \
            ch16[nt][r] = (_Float16)cc[nt * 16 + lb][r];                      \
    frag_cd acc[4][2];                                                        \
    _Pragma("unroll")                                                         \
    for (int nt = 0; nt < 4; ++nt)                                            \
        _Pragma("unroll")                                                     \
        for (int ct = 0; ct < 2; ++ct)                                        \
            acc[nt][ct] = (frag_cd){0.f, 0.f, 0.f, 0.f};                      \
    size_t wrow[3][2];                                                        \
    _Pragma("unroll")                                                         \
    for (int r = 0; r < 3; ++r)                                               \
        _Pragma("unroll")                                                     \
        for (int ct = 0; ct < 2; ++ct)                                        \
            wrow[r][ct] = ((size_t)(r * 128 + w32 + ct * 16 + lb)) * 256 + q * 8; \
    {                                                                         \
        frag_h bF[3][6];                                                      \
        auto loadB = [&](int c, int buf) {                                    \
            _Pragma("unroll")                                                 \
            for (int r = 0; r < 3; ++r)                                       \
                _Pragma("unroll")                                             \
                for (int ct = 0; ct < 2; ++ct)                                \
                    bF[buf][r * 2 + ct] = *(const frag_h*)((Wa_) + wrow[r][ct] + c * 32); \
        };                                                                    \
        loadB(0, 0);                                                          \
        loadB(1, 1);                                                          \
        frag_h aL[2][4];                                                      \
        _Pragma("unroll")                                                     \
        for (int nt = 0; nt < 4; ++nt)                                        \
            aL[0][nt] = *(const frag_h*)&As[nt * 16 + lb][q * 8];             \
        _Pragma("unroll")                                                     \
        for (int ch = 0; ch < 8; ++ch) {                                      \
            if (ch + 2 < 8) loadB(ch + 2, (ch + 2) % 3);                      \
            if (ch + 1 < 8) {                                                 \
                const int c1 = ch + 1;                                        \
                _Pragma("unroll")                                             \
                for (int nt = 0; nt < 4; ++nt)                                \
                    aL[c1 & 1][nt] = (c1 < 4)                                 \
                        ? *(const frag_h*)&As[nt * 16 + lb][c1 * 32 + q * 8]  \
                        : *(const frag_h*)&Ss[nt * 16 + lb][(c1 - 4) * 32 + q * 8]; \
            }                                                                 \
            const int cur = ch % 3;                                           \
            _Pragma("unroll")                                                 \
            for (int r = 0; r < 3; ++r)                                       \
                _Pragma("unroll")                                             \
                for (int nt = 0; nt < 4; ++nt) {                              \
                    frag_h sa = aL[ch & 1][nt] * ch16[nt][r];                 \
                    _Pragma("unroll")                                         \
                    for (int ct = 0; ct < 2; ++ct)                            \
                        acc[nt][ct] = __builtin_amdgcn_mfma_f32_16x16x32_f16( \
                            sa, bF[cur][r * 2 + ct], acc[nt][ct], 0, 0, 0);   \
                }                                                             \
        }                                                                     \
    }                                                                         \
    float vv[4][2][4];                                                        \
    _Pragma("unroll")                                                         \
    for (int ct = 0; ct < 2; ++ct) {                                          \
        int col = w32 + ct * 16 + lb;                                         \
        float b0 = (ba_)[col], b1 = (ba_)[128 + col], b2 = (ba_)[256 + col];  \
        _Pragma("unroll")                                                     \
        for (int nt = 0; nt < 4; ++nt)                                        \
            _Pragma("unroll")                                                 \
            for (int rg = 0; rg < 4; ++rg) {                                  \
                int row = nt * 16 + q * 4 + rg;                               \
                float v = acc[nt][ct][rg]                                     \
                        + cc[row][0] * b0 + cc[row][1] * b1 + cc[row][2] * b2;\
                vv[nt][ct][rg] = fmaxf(v, 0.0f);                              \
            }                                                                 \
    }                                                                         \
    _Pragma("unroll")                                                         \
    for (int nt = 0; nt < 4; ++nt)                                            \
        _Pragma("unroll")                                                     \
        for (int rg = 0; rg < 4; ++rg) {                                      \
            float ss = vv[nt][0][rg] * vv[nt][0][rg] + vv[nt][1][rg] * vv[nt][1][rg]; \
            _Pragma("unroll")                                                 \
            for (int m = 1; m < 16; m <<= 1) ss += __shfl_xor(ss, m, 64);     \
            if (lb == 0) red[nt * 16 + q * 4 + rg][wv] = ss;                  \
        }                                                                     \
    __syncthreads();  /* all K-loop LDS reads complete chip-wide here */      \
    _Pragma("unroll")                                                         \
    for (int nt = 0; nt < 4; ++nt)                                            \
        _Pragma("unroll")                                                     \
        for (int rg = 0; rg < 4; ++rg) {                                      \
            int row = nt * 16 + q * 4 + rg;                                   \
            float t = red[row][0] + red[row][1] + red[row][2] + red[row][3];  \
            float inv = 1.0f / fmaxf(sqrtf(t), 1e-12f);                       \
            _Pragma("unroll")                                                 \
            for (int ct = 0; ct < 2; ++ct)                                    \
                Fs[row][w32 + ct * 16 + lb] = (_Float16)(vv[nt][ct][rg] * inv); \
        }                                                                     \
    __syncthreads();

// ---------------- fused: layer update (norm) + next-layer msg --------------
// LDS: two tiles only; Fs ALIASES As (safe: see macro comment). 36.6 KB.
__global__ __launch_bounds__(256) void fused_upd_msg(
    const float* __restrict__ x,
    const _Float16* __restrict__ Fp, const _Float16* __restrict__ Sp,
    const _Float16* __restrict__ Wa_, const float* __restrict__ ba_,
    const _Float16* __restrict__ Wm2, const float* __restrict__ bm2,
    _Float16* __restrict__ F1, _Float16* __restrict__ Mb)
{
    __shared__ _Float16 ldsbuf[2 * 64 * 136];
    __shared__ float cc[64][3];
    __shared__ float red[64][4];
    _Float16 (*As)[136] = (_Float16(*)[136])ldsbuf;
    _Float16 (*Ss)[136] = (_Float16(*)[136])(ldsbuf + 64 * 136);
    _Float16 (*Fs)[136] = As;   // alias: As dead after K-chunk 3

    const int tid = threadIdx.x;
    const int n0 = blockIdx.x * 64;
    const int lane = tid & 63;
    const int wv = tid >> 6;
    const int q = lane >> 4;
    const int lb = lane & 15;
    const int w32 = wv * 32;

    if (tid < 64) {
        const float* xr = x + (size_t)(n0 + tid) * XSTRIDE;
        cc[tid][0] = 2.0f * xr[0];
        cc[tid][1] = xr[1];
        cc[tid][2] = xr[2];
    }
    STAGE_TILE(As, Fp, n0, tid)
    STAGE_TILE(Ss, Sp, n0, tid)
    __syncthreads();

    UPDATE_PHASE_A_LDS(Wa_, ba_)

    // write F1 global, coalesced 16-B stores from LDS
    #pragma unroll
    for (int i = 0; i < 4; ++i) {
        int idx = i * 256 + tid;             // 0..1023
        int row = idx >> 4, g = idx & 15;
        ((uint4*)F1)[(size_t)(n0 + row) * 16 + g] = *(const uint4*)&Fs[row][g * 8];
    }

    // ---- Phase B: msg GEMM, A from LDS Fs ----
    frag_cd a2[4][2];
    #pragma unroll
    for (int nt = 0; nt < 4; ++nt)
        #pragma unroll
        for (int ct = 0; ct < 2; ++ct)
            a2[nt][ct] = (frag_cd){0.f, 0.f, 0.f, 0.f};

    frag_h bB[4][6];
    #pragma unroll
    for (int c = 0; c < 4; ++c)
        #pragma unroll
        for (int r = 0; r < 3; ++r)
            #pragma unroll
            for (int ct = 0; ct < 2; ++ct)
                bB[c][r * 2 + ct] = *(const frag_h*)(
                    Wm2 + ((size_t)(r * 128 + w32 + ct * 16 + lb)) * 128 + c * 32 + q * 8);

    #pragma unroll
    for (int c = 0; c < 4; ++c) {
        frag_h aM[4];
        #pragma unroll
        for (int nt = 0; nt < 4; ++nt)
            aM[nt] = *(const frag_h*)&Fs[nt * 16 + lb][c * 32 + q * 8];
        #pragma unroll
        for (int r = 0; r < 3; ++r)
            #pragma unroll
            for (int nt = 0; nt < 4; ++nt) {
                frag_h sa = aM[nt] * ch16[nt][r];
                #pragma unroll
                for (int ct = 0; ct < 2; ++ct)
                    a2[nt][ct] = __builtin_amdgcn_mfma_f32_16x16x32_f16(
                        sa, bB[c][r * 2 + ct], a2[nt][ct], 0, 0, 0);
            }
    }

    #pragma unroll
    for (int ct = 0; ct < 2; ++ct) {
        int col = w32 + ct * 16 + lb;
        float b0 = bm2[col], b1 = bm2[128 + col], b2 = bm2[256 + col];
        #pragma unroll
        for (int nt = 0; nt < 4; ++nt)
            #pragma unroll
            for (int rg = 0; rg < 4; ++rg) {
                int row = nt * 16 + q * 4 + rg;
                float v = a2[nt][ct][rg]
                        + cc[row][0] * b0 + cc[row][1] * b1 + cc[row][2] * b2;
                Mb[(size_t)(n0 + row) * 128 + col] = (_Float16)fmaxf(v, 0.0f);
            }
    }
}

// ---------------- fused: layer-2 update + final MLP + log_softmax ----------
// Fs aliases As; Z aliases Ss (Ss dead after K-chunk 7). 36.6 KB LDS.
__global__ __launch_bounds__(256) void fused_upd_final(
    const float* __restrict__ x,
    const _Float16* __restrict__ Fp, const _Float16* __restrict__ Sp,
    const _Float16* __restrict__ Wa_, const float* __restrict__ ba_,
    const _Float16* __restrict__ W1T, const float* __restrict__ b1,
    const _Float16* __restrict__ W2T, const float* __restrict__ b2,
    float* __restrict__ out)
{
    __shared__ _Float16 ldsbuf[2 * 64 * 136];
    __shared__ float cc[64][3];
    __shared__ float red[64][4];
    _Float16 (*As)[136] = (_Float16(*)[136])ldsbuf;
    _Float16 (*Ss)[136] = (_Float16(*)[136])(ldsbuf + 64 * 136);
    _Float16 (*Fs)[136] = As;   // alias
    _Float16 (*Z)[136]  = Ss;   // alias

    const int tid = threadIdx.x;
    const int n0 = blockIdx.x * 64;
    const int lane = tid & 63;
    const int wv = tid >> 6;
    const int q = lane >> 4;
    const int lb = lane & 15;
    const int w32 = wv * 32;

    if (tid < 64) {
        const float* xr = x + (size_t)(n0 + tid) * XSTRIDE;
        cc[tid][0] = 2.0f * xr[0];
        cc[tid][1] = xr[1];
        cc[tid][2] = xr[2];
    }
    STAGE_TILE(As, Fp, n0, tid)
    STAGE_TILE(Ss, Sp, n0, tid)
    __syncthreads();

    UPDATE_PHASE_A_LDS(Wa_, ba_)

    // ---- Phase B: z = F2 @ W1 + b1 (A from LDS Fs) ----
    frag_cd az[4][2];
    #pragma unroll
    for (int nt = 0; nt < 4; ++nt)
        #pragma unroll
        for (int ct = 0; ct < 2; ++ct)
            az[nt][ct] = (frag_cd){0.f, 0.f, 0.f, 0.f};

    frag_h bZ[4][2];
    #pragma unroll
    for (int c = 0; c < 4; ++c)
        #pragma unroll
        for (int ct = 0; ct < 2; ++ct)
            bZ[c][ct] = *(const frag_h*)(
                W1T + (size_t)(w32 + ct * 16 + lb) * 128 + c * 32 + q * 8);

    #pragma unroll
    for (int c = 0; c < 4; ++c) {
        frag_h aZ[4];
        #pragma unroll
        for (int nt = 0; nt < 4; ++nt)
            aZ[nt] = *(const frag_h*)&Fs[nt * 16 + lb][c * 32 + q * 8];
        #pragma unroll
        for (int ct = 0; ct < 2; ++ct)
            #pragma unroll
            for (int nt = 0; nt < 4; ++nt)
                az[nt][ct] = __builtin_amdgcn_mfma_f32_16x16x32_f16(
                    aZ[nt], bZ[c][ct], az[nt][ct], 0, 0, 0);
    }
    __syncthreads();   // Ss K-loop reads done chip-wide before Z overwrite
    #pragma unroll
    for (int ct = 0; ct < 2; ++ct) {
        int col = w32 + ct * 16 + lb;
        float bb = b1[col];
        #pragma unroll
        for (int nt = 0; nt < 4; ++nt)
            #pragma unroll
            for (int rg = 0; rg < 4; ++rg)
                Z[nt * 16 + q * 4 + rg][col] = (_Float16)(az[nt][ct][rg] + bb);
    }
    __syncthreads();

    // ---- Phase C: logits = z@W2 + b2 (wave = 16-row tile), log_softmax ----
    frag_cd a2[3];
    #pragma unroll
    for (int ct = 0; ct < 3; ++ct) a2[ct] = (frag_cd){0.f, 0.f, 0.f, 0.f};
    #pragma unroll
    for (int ch = 0; ch < 4; ++ch) {
        frag_h zF = *(const frag_h*)&Z[wv * 16 + lb][ch * 32 + q * 8];
        #pragma unroll
        for (int ct = 0; ct < 3; ++ct) {
            frag_h bF = *(const frag_h*)(W2T + (size_t)(ct * 16 + lb) * 128 + ch * 32 + q * 8);
            a2[ct] = __builtin_amdgcn_mfma_f32_16x16x32_f16(zF, bF, a2[ct], 0, 0, 0);
        }
    }

    float lg[3][4];
    #pragma unroll
    for (int ct = 0; ct < 3; ++ct) {
        int col = ct * 16 + lb;
        bool valid = col < 40;
        float bb = valid ? b2[col] : -1e30f;
        #pragma unroll
        for (int rg = 0; rg < 4; ++rg)
            lg[ct][rg] = valid ? (a2[ct][rg] + bb) : -1e30f;
    }
    #pragma unroll
    for (int rg = 0; rg < 4; ++rg) {
        float mx = fmaxf(fmaxf(lg[0][rg], lg[1][rg]), lg[2][rg]);
        #pragma unroll
        for (int m = 1; m < 16; m <<= 1) mx = fmaxf(mx, __shfl_xor(mx, m, 64));
        float sm = __expf(lg[0][rg] - mx) + __expf(lg[1][rg] - mx) + __expf(lg[2][rg] - mx);
        #pragma unroll
        for (int m = 1; m < 16; m <<= 1) sm += __shfl_xor(sm, m, 64);
        float ls = mx + __logf(sm);
        int row = n0 + wv * 16 + q * 4 + rg;
        #pragma unroll
        for (int ct = 0; ct < 3; ++ct) {
            int col = ct * 16 + lb;
            if (col < 40) out[(size_t)row * 40 + col] = lg[ct][rg] - ls;
        }
    }
}

extern "C" void kernel_launch(void* const* d_in, const int* in_sizes, int n_in,
                              void* d_out, int out_size, void* d_ws, size_t ws_size,
                              hipStream_t stream) {
    const float* x  = (const float*)d_in[0];
    const int*   ei = (const int*)d_in[1];
    const float* Wm = (const float*)d_in[2];
    const float* bm = (const float*)d_in[3];
    const float* Wa = (const float*)d_in[4];
    const float* ba = (const float*)d_in[5];
    const float* W1 = (const float*)d_in[6];
    const float* b1 = (const float*)d_in[7];
    const float* W2 = (const float*)d_in[8];
    const float* b2 = (const float*)d_in[9];
    float* out = (float*)d_out;

    const int N = in_sizes[0] / XSTRIDE;   // 40000
    const int E = in_sizes[1] / 2;         // 480000
    const int NB = (N + 255) / 256;        // 157
    const size_t P = (size_t)N * 128;      // plane elements

    // workspace carve (16B-aligned)
    _Float16* Mb  = (_Float16*)d_ws;       // msg fp16
    _Float16* X   = Mb + P;                // x feats fp16
    _Float16* S   = X + P;                 // aggr fp16
    _Float16* F1  = S + P;                 // layer-1 out fp16
    _Float16* WmT = F1 + P;
    _Float16* WaT = WmT + CW_M;
    _Float16* W1T = WaT + CW_A;
    _Float16* W2T = W1T + CW_1;
    int* cnt   = (int*)(W2T + CW_2);       // N (memset together with fc)
    int* fc    = cnt + N;                  // N
    int* offs  = fc + N;                   // N+1
    int* csr   = offs + N + 1;             // E
    int* bsums = csr + E;                  // NB

    // ---- prep: zero counters, then merged convert+count ----
    hipMemsetAsync(cnt, 0, (size_t)2 * N * sizeof(int), stream);
    const int prep_total = CW_TOT + N * 16 + E;
    prep_kernel<<<(prep_total + 255) / 256, 256, 0, stream>>>(
        Wm, Wa, W1, W2, WmT, WaT, W1T, W2T, x, X, ei, cnt, N, E);

    // ---- CSR: scanA -> scanC(inline scanB) -> fill ----
    scanA<<<NB, 256, 0, stream>>>(cnt, N, bsums);
    scanC<<<NB, 256, 0, stream>>>(cnt, N, NB, bsums, offs);
    fill_kernel<<<(E + 255) / 256, 256, 0, stream>>>(ei, E, offs, fc, csr);

    const int gblk = N / 64;               // 625
    const int ablk = (N + 15) / 16;        // 2500

    // layer 1 msg
    msg_kernel<<<gblk, 256, 0, stream>>>(x, X, WmT, bm, Mb);
    agg_kernel<<<ablk, 256, 0, stream>>>(csr, offs, Mb, S, N);
    // layer-1 update + layer-2 msg (fused)
    fused_upd_msg<<<gblk, 256, 0, stream>>>(
        x, X, S, WaT, ba,
        WmT + (size_t)3 * 128 * 128, bm + (size_t)4 * 128, F1, Mb);
    agg_kernel<<<ablk, 256, 0, stream>>>(csr, offs, Mb, S, N);
    // layer-2 update + final MLP + log_softmax (fused)
    fused_upd_final<<<gblk, 256, 0, stream>>>(
        x, F1, S, WaT + (size_t)3 * 128 * 256, ba + (size_t)4 * 128,
        W1T, b1, W2T, b2, out);
}